// Round 1
// baseline (287.739 us; speedup 1.0000x reference)
//
#include <hip/hip_runtime.h>

// Problem constants
#define B_    512
#define D_TRF 5120
#define P_    32
#define E_    160
#define D_OUT 3000
#define PAD_  61
#define D_CL  4998
#define INV_SCALE 0.07905694150420949f   // 1/sqrt(160)
#define N_PAD 3072          // lin_w rows padded (64 tiles of 48)

typedef __attribute__((ext_vector_type(4))) float floatx4;
typedef __attribute__((ext_vector_type(16))) float floatx16;
typedef __attribute__((ext_vector_type(8))) short short8;

static __device__ __forceinline__ unsigned short f2bf(float f) {
    unsigned int u = __float_as_uint(f);
    unsigned int r = (u + 0x7fffu + ((u >> 16) & 1u)) >> 16;
    return (unsigned short)r;
}
static __device__ __forceinline__ float bf2f(unsigned short u) {
    return __uint_as_float(((unsigned int)u) << 16);
}
static __device__ __forceinline__ void load_lds16(const void* g, void* lds) {
    __builtin_amdgcn_global_load_lds(
        (const __attribute__((address_space(1))) unsigned int*)g,
        (__attribute__((address_space(3))) unsigned int*)lds, 16, 0, 0);
}

// ---------------------------------------------------------------------------
// K0: cast lin_w [3000,5120] f32 -> [3072,5120] bf16 (pad rows zeroed)
// ---------------------------------------------------------------------------
__global__ __launch_bounds__(256) void k_castw(const float* __restrict__ w,
                                               unsigned short* __restrict__ wb) {
    size_t i4 = ((size_t)blockIdx.x * 256 + threadIdx.x) * 4;
    size_t o = i4 / D_TRF;
    ushort4 s;
    if (o < D_OUT) {
        float4 v = *(const float4*)(w + i4);
        s.x = f2bf(v.x); s.y = f2bf(v.y); s.z = f2bf(v.z); s.w = f2bf(v.w);
    } else {
        s.x = s.y = s.z = s.w = 0;
    }
    *(ushort4*)(wb + i4) = s;
}

// ---------------------------------------------------------------------------
// K0b: cast wq/wk/wv ([f][e], already B-operand layout) to bf16;
//      transpose bt_w -> wtb[f][e] = bt_w[e][f].
// ---------------------------------------------------------------------------
__global__ __launch_bounds__(256) void k_cast_small(const float* __restrict__ wq,
                                                    const float* __restrict__ wk,
                                                    const float* __restrict__ wv,
                                                    const float* __restrict__ btw,
                                                    unsigned short* __restrict__ wqb,
                                                    unsigned short* __restrict__ wkb,
                                                    unsigned short* __restrict__ wvb,
                                                    unsigned short* __restrict__ wtb) {
    int idx = blockIdx.x * 256 + threadIdx.x;   // < 25600
    wqb[idx] = f2bf(wq[idx]);
    wkb[idx] = f2bf(wk[idx]);
    wvb[idx] = f2bf(wv[idx]);
    int f = idx / E_, e = idx - f * E_;
    wtb[idx] = f2bf(btw[(size_t)e * E_ + f]);
}

// ---------------------------------------------------------------------------
// K1: cl = (x*std+mean) @ mat, with 61-zero pad both sides -> [512,5120]
// ---------------------------------------------------------------------------
__global__ __launch_bounds__(256) void k_cl(const float* __restrict__ x,
                                            const float* __restrict__ stdv,
                                            const float* __restrict__ meanv,
                                            const float* __restrict__ mat,
                                            float* __restrict__ cl) {
    int bg = blockIdx.x, jc = blockIdx.y, tid = threadIdx.x;
    __shared__ float t[8 * 64];
    for (int idx = tid; idx < 8 * 64; idx += 256) {
        int i = idx >> 6, k = idx & 63;
        t[idx] = x[(size_t)(bg * 8 + i) * 64 + k] * stdv[k] + meanv[k];
    }
    __syncthreads();

    if (jc == 0) {
        for (int idx = tid; idx < 8 * PAD_; idx += 256) {
            int i = idx / PAD_, jj = idx - i * PAD_;
            cl[(size_t)(bg * 8 + i) * D_TRF + jj] = 0.f;
        }
    } else if (jc == 3) {
        for (int idx = tid; idx < 8 * PAD_; idx += 256) {
            int i = idx / PAD_, jj = idx - i * PAD_;
            cl[(size_t)(bg * 8 + i) * D_TRF + (D_TRF - PAD_) + jj] = 0.f;
        }
    }

    int j0 = jc * 1250;
    int jend = min(D_CL, j0 + 1250);
    for (int j = j0 + tid; j < jend; j += 256) {
        float acc[8] = {};
        #pragma unroll 16
        for (int k = 0; k < 64; ++k) {
            float m = mat[(size_t)k * D_CL + j];
            #pragma unroll
            for (int i = 0; i < 8; ++i) acc[i] += t[i * 64 + k] * m;
        }
        #pragma unroll
        for (int i = 0; i < 8; ++i)
            cl[(size_t)(bg * 8 + i) * D_TRF + PAD_ + j] = acc[i];
    }
}

// ---------------------------------------------------------------------------
// K2: LayerNorm cl row -> xn bf16 [16384,160]. grid = 512 (one b each)
// ---------------------------------------------------------------------------
__global__ __launch_bounds__(256) void k_ln(const float* __restrict__ cl,
                                            const float* __restrict__ ln_g,
                                            const float* __restrict__ ln_b,
                                            unsigned short* __restrict__ xn) {
    int b = blockIdx.x, tid = threadIdx.x;
    __shared__ float redA[4], redB[4];
    __shared__ float sMu, sRstd;
    const float* row = cl + (size_t)b * D_TRF;

    float s = 0.f, s2 = 0.f;
    #pragma unroll
    for (int it = 0; it < 5; ++it) {
        int i4 = (it * 256 + tid) * 4;
        float4 v = *(const float4*)(row + i4);
        s += v.x + v.y + v.z + v.w;
        s2 += v.x * v.x + v.y * v.y + v.z * v.z + v.w * v.w;
    }
    #pragma unroll
    for (int off = 32; off; off >>= 1) {
        s  += __shfl_down(s, off);
        s2 += __shfl_down(s2, off);
    }
    if ((tid & 63) == 0) { redA[tid >> 6] = s; redB[tid >> 6] = s2; }
    __syncthreads();
    if (tid == 0) {
        float S = redA[0] + redA[1] + redA[2] + redA[3];
        float S2 = redB[0] + redB[1] + redB[2] + redB[3];
        float mu = S / (float)D_TRF;
        float var = S2 / (float)D_TRF - mu * mu;
        sMu = mu; sRstd = rsqrtf(var + 1e-5f);
    }
    __syncthreads();
    float mu = sMu, rs = sRstd;
    #pragma unroll
    for (int it = 0; it < 5; ++it) {
        int i4 = (it * 256 + tid) * 4;
        float4 v = *(const float4*)(row + i4);
        float4 g = *(const float4*)(ln_g + i4);
        float4 be = *(const float4*)(ln_b + i4);
        ushort4 o;
        o.x = f2bf((v.x - mu) * rs * g.x + be.x);
        o.y = f2bf((v.y - mu) * rs * g.y + be.y);
        o.z = f2bf((v.z - mu) * rs * g.z + be.z);
        o.w = f2bf((v.w - mu) * rs * g.w + be.w);
        *(ushort4*)(xn + (size_t)b * D_TRF + i4) = o;
    }
}

// ---------------------------------------------------------------------------
// K3: QKV via MFMA, register-resident B-frags loaded straight from global.
// V is stored TRANSPOSED per b: Vt[b*5120 + e*32 + q] (q contiguous) so the
// attention PV B-frags become single 16B vector loads.
// ---------------------------------------------------------------------------
__global__ __launch_bounds__(256) void k_qkv3(const unsigned short* __restrict__ xn,
                                              const unsigned short* __restrict__ wqb,
                                              const unsigned short* __restrict__ wkb,
                                              const unsigned short* __restrict__ wvb,
                                              const float* __restrict__ bq,
                                              const float* __restrict__ bk,
                                              const float* __restrict__ bv,
                                              unsigned short* __restrict__ Qb,
                                              unsigned short* __restrict__ Kb,
                                              unsigned short* __restrict__ Vt) {
    int tid = threadIdx.x, wid = tid >> 6, lane = tid & 63;
    int l16 = lane & 15, quad = lane >> 4;
    int m0 = blockIdx.x * 64 + wid * 16;
    int sel = blockIdx.y;                 // 0..5
    int mat = sel >> 1;
    int cf0 = (sel & 1) * 5;

    const unsigned short* wsrc = (mat == 0) ? wqb : (mat == 1) ? wkb : wvb;
    const float* bias          = (mat == 0) ? bq  : (mat == 1) ? bk  : bv;
    unsigned short* outp       = (mat == 0) ? Qb  : Kb;

    short8 a[5];
    const unsigned short* arow = xn + (size_t)(m0 + l16) * E_ + quad * 8;
    #pragma unroll
    for (int kc = 0; kc < 5; ++kc) a[kc] = *(const short8*)(arow + kc * 32);

    #pragma unroll
    for (int c = 0; c < 5; ++c) {
        int cf = cf0 + c;
        floatx4 acc = {0.f, 0.f, 0.f, 0.f};
        const unsigned short* bp = wsrc + (size_t)(cf * 16 + l16) * E_ + quad * 8;
        #pragma unroll
        for (int kc = 0; kc < 5; ++kc) {
            short8 bf = *(const short8*)(bp + kc * 32);
            acc = __builtin_amdgcn_mfma_f32_16x16x32_bf16(a[kc], bf, acc, 0, 0, 0);
        }
        int col = cf * 16 + l16;
        float bb = bias[col];
        if (mat == 2) {
            // transposed store: Vt[b][e=col][q=p]
            #pragma unroll
            for (int r = 0; r < 4; ++r) {
                int row = m0 + quad * 4 + r;
                int b_ = row >> 5, p = row & 31;
                Vt[(size_t)b_ * D_TRF + col * 32 + p] = f2bf(acc[r] + bb);
            }
        } else {
            size_t o = (size_t)(m0 + quad * 4) * E_ + col;
            #pragma unroll
            for (int r = 0; r < 4; ++r)
                outp[o + (size_t)r * E_] = f2bf(acc[r] + bb);
        }
    }
}

// ---------------------------------------------------------------------------
// K4: MFMA attention v4, 4 waves per b (grid 512 x 256). All waves compute
// S = QK^T redundantly; softmax over p in-reg; wave 0 writes att->LDS;
// waves split the 5 PV e-chunks. PV B-frags = vector loads from Vt
// (B[n=e][k=q] = Vt[e*32+q], q-contiguous) — replaces 8 scalar loads each.
// ---------------------------------------------------------------------------
__global__ __launch_bounds__(256) void k_attn4(const unsigned short* __restrict__ Q,
                                               const unsigned short* __restrict__ K,
                                               const unsigned short* __restrict__ Vt,
                                               const float* __restrict__ cl,
                                               const float* __restrict__ bt_gain,
                                               const float* __restrict__ bt_bias,
                                               float* __restrict__ h,
                                               unsigned short* __restrict__ x2b) {
    int b = blockIdx.x;
    int tid = threadIdx.x, wid = tid >> 6, lane = tid & 63;
    int l32 = lane & 31, hi = lane >> 5;
    __shared__ __align__(16) unsigned short Satt[32 * 40];   // row stride 40 bf16

    const unsigned short* Qg = Q + (size_t)b * D_TRF;
    const unsigned short* Kg = K + (size_t)b * D_TRF;
    const unsigned short* Vg = Vt + (size_t)b * D_TRF;

    // ---- S = Q K^T (redundant per wave) ----
    floatx16 S = {0.f, 0.f, 0.f, 0.f, 0.f, 0.f, 0.f, 0.f,
                  0.f, 0.f, 0.f, 0.f, 0.f, 0.f, 0.f, 0.f};
    #pragma unroll
    for (int kc = 0; kc < 10; ++kc) {
        int e0 = kc * 16;
        short8 aq = *(const short8*)(Qg + l32 * E_ + e0 + hi * 8);
        short8 bk = *(const short8*)(Kg + l32 * E_ + e0 + hi * 8);
        S = __builtin_amdgcn_mfma_f32_32x32x16_bf16(aq, bk, S, 0, 0, 0);
    }

    // ---- softmax over p (C-layout rows): in-lane 16 regs + shfl_xor(32) ----
    float mx = -1e30f;
    #pragma unroll
    for (int r = 0; r < 16; ++r) { S[r] *= INV_SCALE; mx = fmaxf(mx, S[r]); }
    mx = fmaxf(mx, __shfl_xor(mx, 32));
    float ex[16];
    float sum = 0.f;
    #pragma unroll
    for (int r = 0; r < 16; ++r) { ex[r] = expf(S[r] - mx); sum += ex[r]; }
    sum += __shfl_xor(sum, 32);
    float inv = 1.f / sum;

    // ---- att -> LDS [p][q] bf16 (wave 0 only) ----
    if (wid == 0) {
        #pragma unroll
        for (int r = 0; r < 16; ++r) {
            int p = (r & 3) + 8 * (r >> 2) + 4 * hi;
            Satt[p * 40 + l32] = f2bf(ex[r] * inv);
        }
    }
    __syncthreads();

    // ---- A-frags for PV ----
    short8 a0 = *(const short8*)(&Satt[l32 * 40 + hi * 8]);
    short8 a1 = *(const short8*)(&Satt[l32 * 40 + 16 + hi * 8]);

    const float* clr = cl + (size_t)b * D_TRF;
    float gg = bt_gain[0], bb2 = bt_bias[0];

    for (int t = wid; t < 5; t += 4) {
        int e0 = t * 32;
        short8 b0 = *(const short8*)(Vg + (e0 + l32) * 32 + hi * 8);
        short8 b1 = *(const short8*)(Vg + (e0 + l32) * 32 + 16 + hi * 8);
        floatx16 acc = {0.f, 0.f, 0.f, 0.f, 0.f, 0.f, 0.f, 0.f,
                        0.f, 0.f, 0.f, 0.f, 0.f, 0.f, 0.f, 0.f};
        acc = __builtin_amdgcn_mfma_f32_32x32x16_bf16(a0, b0, acc, 0, 0, 0);
        acc = __builtin_amdgcn_mfma_f32_32x32x16_bf16(a1, b1, acc, 0, 0, 0);
        #pragma unroll
        for (int r = 0; r < 16; ++r) {
            int p = (r & 3) + 8 * (r >> 2) + 4 * hi;
            int idx = p * E_ + e0 + l32;
            float hv = acc[r] + clr[idx];
            h[(size_t)b * D_TRF + idx] = hv;
            x2b[(size_t)b * D_TRF + idx] = f2bf(hv * gg + bb2);
        }
    }
}

// ---------------------------------------------------------------------------
// K5: Better_Transformer via MFMA, register B-frags from global (no LDS).
// ---------------------------------------------------------------------------
__global__ __launch_bounds__(256) void k_bt3(const unsigned short* __restrict__ x2b,
                                             const unsigned short* __restrict__ wtb,
                                             const float* __restrict__ bt_b,
                                             const float* __restrict__ sup_g,
                                             const float* __restrict__ sup_b,
                                             const float* __restrict__ h,
                                             unsigned short* __restrict__ yb) {
    int tid = threadIdx.x, wid = tid >> 6, lane = tid & 63;
    int l16 = lane & 15, quad = lane >> 4;
    int m0 = blockIdx.x * 64 + wid * 16;
    int cf0 = blockIdx.y * 5;

    short8 a[5];
    const unsigned short* arow = x2b + (size_t)(m0 + l16) * E_ + quad * 8;
    #pragma unroll
    for (int kc = 0; kc < 5; ++kc) a[kc] = *(const short8*)(arow + kc * 32);

    #pragma unroll
    for (int c = 0; c < 5; ++c) {
        int cf = cf0 + c;
        floatx4 acc = {0.f, 0.f, 0.f, 0.f};
        const unsigned short* bp = wtb + (size_t)(cf * 16 + l16) * E_ + quad * 8;
        #pragma unroll
        for (int kc = 0; kc < 5; ++kc) {
            short8 bf = *(const short8*)(bp + kc * 32);
            acc = __builtin_amdgcn_mfma_f32_16x16x32_bf16(a[kc], bf, acc, 0, 0, 0);
        }
        int col = cf * 16 + l16;
        float bb = bt_b[col];
        #pragma unroll
        for (int r = 0; r < 4; ++r) {
            int row = m0 + quad * 4 + r;
            int p = row & 31;
            int i = p * E_ + col;
            float o = acc[r] + bb;
            float sig = 1.f / (1.f + expf(-sup_b[i] * o));
            float y = (sup_g[i] + sig * (1.f - sup_g[i])) * o + h[(size_t)row * E_ + col];
            yb[(size_t)row * E_ + col] = f2bf(y);
        }
    }
}

// ---------------------------------------------------------------------------
// K7: head GEMM v8 — m-split-2 of k_lin7 for 2 blocks/CU.
// k_lin7 (50.6 us) was latency-bound: grid 256 = 1 block/CU, so the
// stage->drain->compute barriers had nothing to hide under and only
// 2 waves/SIMD covered A-load latency (MfmaUtil 11.6%, HBM 15%, Occ 19%).
// v8: grid 512 = 64 nt x 4 sp x 2 m-halves; each block = 256 rows x 48 cols,
// 8 waves x 32 rows, acc[2][3]. LDS stays 60 KB -> exactly 2 blocks/CU
// (16 waves/CU): co-resident block computes while the other stages/drains,
// and 4 waves/SIMD double the outstanding-load coverage.
// B is staged by both m-halves of a pair; bid decode puts the pair on the
// SAME XCD (bid%8 equal, 8 apart in dispatch) so the 2nd stage is an L2 hit.
// ---------------------------------------------------------------------------
__global__ __launch_bounds__(512, 4) void k_lin8(const unsigned short* __restrict__ yb,
                                                 const unsigned short* __restrict__ wb,
                                                 float* __restrict__ pb) {
    __shared__ __align__(16) unsigned short Bs[48 * 640];   // 60 KB
    int bid = blockIdx.x;
    // xcd = bid % 8 (round-robin). Pair (mh=0/1) shares x -> same XCD.
    int x = bid & 7, mh = (bid >> 3) & 1, g = bid >> 4;     // g in [0,32)
    int idx = g * 8 + x;                                    // (nt,sp) in [0,256)
    int nt = idx & 63, sp = idx >> 6;
    int tid = threadIdx.x, wid = tid >> 6, lane = tid & 63;
    int l16 = lane & 15, quad = lane >> 4;
    int br7 = l16 & 7;

    floatx4 acc[2][3];
    #pragma unroll
    for (int i = 0; i < 2; ++i)
        #pragma unroll
        for (int j = 0; j < 3; ++j) acc[i][j] = (floatx4){0.f, 0.f, 0.f, 0.f};

    int bbase[3];
    #pragma unroll
    for (int fj = 0; fj < 3; ++fj) bbase[fj] = (fj * 16 + l16) * 640;

    const int mrow0 = mh * 256 + wid * 32;
    const int k0 = sp * 1280;
    for (int h = 0; h < 2; ++h) {
        int kh = k0 + h * 640;
        if (h) __syncthreads();              // all waves done reading half 0
        #pragma unroll
        for (int i = 0; i < 8; ++i) {        // 3840 slots of 16 B, 512 thr
            int u = i * 512 + tid;
            if (u < 3840) {                  // boundary at wave edge (3840=7.5*512)
                int row = u / 80;            // 80 chunks per row
                int c = u - row * 80;
                int gx = c ^ (row & 7);      // XOR swizzle on global side
                load_lds16(wb + (size_t)(nt * 48 + row) * D_TRF + kh + gx * 8,
                           (char*)Bs + (size_t)u * 16);
            }
        }
        __syncthreads();

        const unsigned short* Ar[2];
        #pragma unroll
        for (int fi = 0; fi < 2; ++fi)
            Ar[fi] = yb + (size_t)(mrow0 + fi * 16 + l16) * D_TRF + quad * 8 + kh;

        short8 aP[2], bP[3], aN[2], bN[3];
        #pragma unroll
        for (int fi = 0; fi < 2; ++fi) aP[fi] = *(const short8*)(Ar[fi]);
        #pragma unroll
        for (int fj = 0; fj < 3; ++fj)
            bP[fj] = *(const short8*)(Bs + bbase[fj] + ((quad ^ br7) * 8));

        for (int it = 0; it < 10; ++it) {
            int s1 = 2 * it + 1;
            #pragma unroll
            for (int fi = 0; fi < 2; ++fi)
                aN[fi] = *(const short8*)(Ar[fi] + s1 * 32);
            #pragma unroll
            for (int fj = 0; fj < 3; ++fj) {
                int c = s1 * 4 + quad;
                bN[fj] = *(const short8*)(Bs + bbase[fj] + ((c ^ br7) * 8));
            }
            #pragma unroll
            for (int fi = 0; fi < 2; ++fi)
                #pragma unroll
                for (int fj = 0; fj < 3; ++fj)
                    acc[fi][fj] = __builtin_amdgcn_mfma_f32_16x16x32_bf16(
                        aP[fi], bP[fj], acc[fi][fj], 0, 0, 0);

            int s2 = (it < 9) ? 2 * it + 2 : 0;   // wrap: dummy, unused
            #pragma unroll
            for (int fi = 0; fi < 2; ++fi)
                aP[fi] = *(const short8*)(Ar[fi] + s2 * 32);
            #pragma unroll
            for (int fj = 0; fj < 3; ++fj) {
                int c = s2 * 4 + quad;
                bP[fj] = *(const short8*)(Bs + bbase[fj] + ((c ^ br7) * 8));
            }
            #pragma unroll
            for (int fi = 0; fi < 2; ++fi)
                #pragma unroll
                for (int fj = 0; fj < 3; ++fj)
                    acc[fi][fj] = __builtin_amdgcn_mfma_f32_16x16x32_bf16(
                        aN[fi], bN[fj], acc[fi][fj], 0, 0, 0);
        }
    }

    // epilogue: plain coalesced stores of partials
    #pragma unroll
    for (int fi = 0; fi < 2; ++fi) {
        int row = mrow0 + fi * 16 + quad * 4;
        #pragma unroll
        for (int fj = 0; fj < 3; ++fj) {
            int col = nt * 48 + fj * 16 + l16;
            #pragma unroll
            for (int r = 0; r < 4; ++r)
                pb[((size_t)(sp * 512 + row + r)) * 3072 + col] = acc[fi][fj][r];
        }
    }
}

// ---------------------------------------------------------------------------
// K8: reduce 4 split-K partials + bias/gain -> out [512,3000]
// ---------------------------------------------------------------------------
__global__ __launch_bounds__(256) void k_red(const float* __restrict__ pb,
                                             const float* __restrict__ lin_b,
                                             const float* __restrict__ out_gain,
                                             const float* __restrict__ out_bias,
                                             float* __restrict__ out) {
    int col = blockIdx.x * 256 + threadIdx.x;
    if (col >= D_OUT) return;
    int row = blockIdx.y;
    size_t base = (size_t)row * 3072 + col;
    const size_t stride = (size_t)512 * 3072;
    float s = pb[base] + pb[base + stride] + pb[base + 2 * stride] + pb[base + 3 * stride];
    float g = out_gain[0];
    out[(size_t)row * D_OUT + col] = s * g + lin_b[col] * g + out_bias[0];
}

// ---------------------------------------------------------------------------
// Workspace layout (bytes)
// ---------------------------------------------------------------------------
#define SZ_ROWF ((size_t)B_ * D_TRF * 4)           // 10,485,760
#define SZ_ROWB ((size_t)B_ * D_TRF * 2)           // 5,242,880
#define OFF_CL  ((size_t)0)
#define OFF_H   (OFF_CL + SZ_ROWF)
#define OFF_XN  (OFF_H + SZ_ROWF)                  // xn bf16; reused as x2b
#define OFF_QB  (OFF_XN + SZ_ROWB)
#define OFF_KB  (OFF_QB + SZ_ROWB)
#define OFF_VB  (OFF_KB + SZ_ROWB)                 // holds Vt [b][e][q]
#define OFF_YB  (OFF_VB + SZ_ROWB)
#define OFF_WSM (OFF_YB + SZ_ROWB)                 // 4 x 51200 B
#define OFF_WB  (OFF_WSM + (size_t)4 * E_ * E_ * 2)
// end = OFF_WB + 3072*5120*2 = 78,848,000 bytes
// pb (head-GEMM partials, 4*512*3072*4 = 25,165,824 B) aliases OFF_CL..:
// cl/h/xn are all dead once k_bt3 has run, and 25.2 MB < OFF_QB (26.2 MB).

extern "C" void kernel_launch(void* const* d_in, const int* in_sizes, int n_in,
                              void* d_out, int out_size, void* d_ws, size_t ws_size,
                              hipStream_t stream) {
    const float* x        = (const float*)d_in[0];
    const float* stdv     = (const float*)d_in[1];
    const float* meanv    = (const float*)d_in[2];
    const float* mat      = (const float*)d_in[3];
    const float* ln_g     = (const float*)d_in[4];
    const float* ln_b     = (const float*)d_in[5];
    const float* wq       = (const float*)d_in[6];
    const float* bq       = (const float*)d_in[7];
    const float* wk       = (const float*)d_in[8];
    const float* bk       = (const float*)d_in[9];
    const float* wv       = (const float*)d_in[10];
    const float* bv       = (const float*)d_in[11];
    const float* bt_w     = (const float*)d_in[12];
    const float* bt_b     = (const float*)d_in[13];
    const float* bt_gain  = (const float*)d_in[14];
    const float* bt_bias  = (const float*)d_in[15];
    const float* sup_g    = (const float*)d_in[16];
    const float* sup_b    = (const float*)d_in[17];
    const float* lin_w    = (const float*)d_in[18];
    const float* lin_b    = (const float*)d_in[19];
    const float* out_gain = (const float*)d_in[20];
    const float* out_bias = (const float*)d_in[21];

    char* ws = (char*)d_ws;
    float* cl = (float*)(ws + OFF_CL);
    float* h  = (float*)(ws + OFF_H);
    unsigned short* xn  = (unsigned short*)(ws + OFF_XN);
    unsigned short* x2b = xn;   // xn dead after k_qkv3
    unsigned short* Qb  = (unsigned short*)(ws + OFF_QB);
    unsigned short* Kb  = (unsigned short*)(ws + OFF_KB);
    unsigned short* Vt  = (unsigned short*)(ws + OFF_VB);
    unsigned short* yb  = (unsigned short*)(ws + OFF_YB);
    unsigned short* wqb = (unsigned short*)(ws + OFF_WSM);
    unsigned short* wkb = wqb + E_ * E_;
    unsigned short* wvb = wkb + E_ * E_;
    unsigned short* wtb = wvb + E_ * E_;
    unsigned short* wb  = (unsigned short*)(ws + OFF_WB);
    float* pb = (float*)(ws + OFF_CL);   // aliases cl/h/xn (dead by k_lin8)
    float* out = (float*)d_out;

    k_castw<<<15360, 256, 0, stream>>>(lin_w, wb);
    k_cast_small<<<100, 256, 0, stream>>>(wq, wk, wv, bt_w, wqb, wkb, wvb, wtb);
    k_cl<<<dim3(64, 4), 256, 0, stream>>>(x, stdv, meanv, mat, cl);
    k_ln<<<512, 256, 0, stream>>>(cl, ln_g, ln_b, xn);
    k_qkv3<<<dim3(256, 6), 256, 0, stream>>>(xn, wqb, wkb, wvb, bq, bk, bv, Qb, Kb, Vt);
    k_attn4<<<512, 256, 0, stream>>>(Qb, Kb, Vt, cl, bt_gain, bt_bias, h, x2b);
    k_bt3<<<dim3(256, 2), 256, 0, stream>>>(x2b, wtb, bt_b, sup_g, sup_b, h, yb);
    k_lin8<<<512, 512, 0, stream>>>(yb, wb, pb);
    k_red<<<dim3(12, 512), 256, 0, stream>>>(pb, lin_b, out_gain, out_bias, out);
}

// Round 3
// 276.486 us; speedup vs baseline: 1.0407x; 1.0407x over previous
//
#include <hip/hip_runtime.h>

// Problem constants
#define B_    512
#define D_TRF 5120
#define P_    32
#define E_    160
#define D_OUT 3000
#define PAD_  61
#define D_CL  4998
#define INV_SCALE 0.07905694150420949f   // 1/sqrt(160)
#define N_PAD 3072          // lin_w rows padded (64 tiles of 48 / 32 tiles of 96)

typedef __attribute__((ext_vector_type(4))) float floatx4;
typedef __attribute__((ext_vector_type(16))) float floatx16;
typedef __attribute__((ext_vector_type(8))) short short8;

static __device__ __forceinline__ unsigned short f2bf(float f) {
    unsigned int u = __float_as_uint(f);
    unsigned int r = (u + 0x7fffu + ((u >> 16) & 1u)) >> 16;
    return (unsigned short)r;
}
static __device__ __forceinline__ float bf2f(unsigned short u) {
    return __uint_as_float(((unsigned int)u) << 16);
}
static __device__ __forceinline__ void load_lds16(const void* g, void* lds) {
    __builtin_amdgcn_global_load_lds(
        (const __attribute__((address_space(1))) unsigned int*)g,
        (__attribute__((address_space(3))) unsigned int*)lds, 16, 0, 0);
}

// ---------------------------------------------------------------------------
// K0: cast lin_w [3000,5120] f32 -> [3072,5120] bf16 (pad rows zeroed)
// ---------------------------------------------------------------------------
__global__ __launch_bounds__(256) void k_castw(const float* __restrict__ w,
                                               unsigned short* __restrict__ wb) {
    size_t i4 = ((size_t)blockIdx.x * 256 + threadIdx.x) * 4;
    size_t o = i4 / D_TRF;
    ushort4 s;
    if (o < D_OUT) {
        float4 v = *(const float4*)(w + i4);
        s.x = f2bf(v.x); s.y = f2bf(v.y); s.z = f2bf(v.z); s.w = f2bf(v.w);
    } else {
        s.x = s.y = s.z = s.w = 0;
    }
    *(ushort4*)(wb + i4) = s;
}

// ---------------------------------------------------------------------------
// K0b: cast wq/wk/wv ([f][e], already B-operand layout) to bf16;
//      transpose bt_w -> wtb[f][e] = bt_w[e][f].
// ---------------------------------------------------------------------------
__global__ __launch_bounds__(256) void k_cast_small(const float* __restrict__ wq,
                                                    const float* __restrict__ wk,
                                                    const float* __restrict__ wv,
                                                    const float* __restrict__ btw,
                                                    unsigned short* __restrict__ wqb,
                                                    unsigned short* __restrict__ wkb,
                                                    unsigned short* __restrict__ wvb,
                                                    unsigned short* __restrict__ wtb) {
    int idx = blockIdx.x * 256 + threadIdx.x;   // < 25600
    wqb[idx] = f2bf(wq[idx]);
    wkb[idx] = f2bf(wk[idx]);
    wvb[idx] = f2bf(wv[idx]);
    int f = idx / E_, e = idx - f * E_;
    wtb[idx] = f2bf(btw[(size_t)e * E_ + f]);
}

// ---------------------------------------------------------------------------
// K1: cl = (x*std+mean) @ mat, with 61-zero pad both sides -> [512,5120]
// ---------------------------------------------------------------------------
__global__ __launch_bounds__(256) void k_cl(const float* __restrict__ x,
                                            const float* __restrict__ stdv,
                                            const float* __restrict__ meanv,
                                            const float* __restrict__ mat,
                                            float* __restrict__ cl) {
    int bg = blockIdx.x, jc = blockIdx.y, tid = threadIdx.x;
    __shared__ float t[8 * 64];
    for (int idx = tid; idx < 8 * 64; idx += 256) {
        int i = idx >> 6, k = idx & 63;
        t[idx] = x[(size_t)(bg * 8 + i) * 64 + k] * stdv[k] + meanv[k];
    }
    __syncthreads();

    if (jc == 0) {
        for (int idx = tid; idx < 8 * PAD_; idx += 256) {
            int i = idx / PAD_, jj = idx - i * PAD_;
            cl[(size_t)(bg * 8 + i) * D_TRF + jj] = 0.f;
        }
    } else if (jc == 3) {
        for (int idx = tid; idx < 8 * PAD_; idx += 256) {
            int i = idx / PAD_, jj = idx - i * PAD_;
            cl[(size_t)(bg * 8 + i) * D_TRF + (D_TRF - PAD_) + jj] = 0.f;
        }
    }

    int j0 = jc * 1250;
    int jend = min(D_CL, j0 + 1250);
    for (int j = j0 + tid; j < jend; j += 256) {
        float acc[8] = {};
        #pragma unroll 16
        for (int k = 0; k < 64; ++k) {
            float m = mat[(size_t)k * D_CL + j];
            #pragma unroll
            for (int i = 0; i < 8; ++i) acc[i] += t[i * 64 + k] * m;
        }
        #pragma unroll
        for (int i = 0; i < 8; ++i)
            cl[(size_t)(bg * 8 + i) * D_TRF + PAD_ + j] = acc[i];
    }
}

// ---------------------------------------------------------------------------
// K2: LayerNorm cl row -> xn bf16 [16384,160]. grid = 512 (one b each)
// ---------------------------------------------------------------------------
__global__ __launch_bounds__(256) void k_ln(const float* __restrict__ cl,
                                            const float* __restrict__ ln_g,
                                            const float* __restrict__ ln_b,
                                            unsigned short* __restrict__ xn) {
    int b = blockIdx.x, tid = threadIdx.x;
    __shared__ float redA[4], redB[4];
    __shared__ float sMu, sRstd;
    const float* row = cl + (size_t)b * D_TRF;

    float s = 0.f, s2 = 0.f;
    #pragma unroll
    for (int it = 0; it < 5; ++it) {
        int i4 = (it * 256 + tid) * 4;
        float4 v = *(const float4*)(row + i4);
        s += v.x + v.y + v.z + v.w;
        s2 += v.x * v.x + v.y * v.y + v.z * v.z + v.w * v.w;
    }
    #pragma unroll
    for (int off = 32; off; off >>= 1) {
        s  += __shfl_down(s, off);
        s2 += __shfl_down(s2, off);
    }
    if ((tid & 63) == 0) { redA[tid >> 6] = s; redB[tid >> 6] = s2; }
    __syncthreads();
    if (tid == 0) {
        float S = redA[0] + redA[1] + redA[2] + redA[3];
        float S2 = redB[0] + redB[1] + redB[2] + redB[3];
        float mu = S / (float)D_TRF;
        float var = S2 / (float)D_TRF - mu * mu;
        sMu = mu; sRstd = rsqrtf(var + 1e-5f);
    }
    __syncthreads();
    float mu = sMu, rs = sRstd;
    #pragma unroll
    for (int it = 0; it < 5; ++it) {
        int i4 = (it * 256 + tid) * 4;
        float4 v = *(const float4*)(row + i4);
        float4 g = *(const float4*)(ln_g + i4);
        float4 be = *(const float4*)(ln_b + i4);
        ushort4 o;
        o.x = f2bf((v.x - mu) * rs * g.x + be.x);
        o.y = f2bf((v.y - mu) * rs * g.y + be.y);
        o.z = f2bf((v.z - mu) * rs * g.z + be.z);
        o.w = f2bf((v.w - mu) * rs * g.w + be.w);
        *(ushort4*)(xn + (size_t)b * D_TRF + i4) = o;
    }
}

// ---------------------------------------------------------------------------
// K3: QKV via MFMA, register-resident B-frags loaded straight from global.
// V is stored TRANSPOSED per b: Vt[b*5120 + e*32 + q] (q contiguous) so the
// attention PV B-frags become single 16B vector loads.
// ---------------------------------------------------------------------------
__global__ __launch_bounds__(256) void k_qkv3(const unsigned short* __restrict__ xn,
                                              const unsigned short* __restrict__ wqb,
                                              const unsigned short* __restrict__ wkb,
                                              const unsigned short* __restrict__ wvb,
                                              const float* __restrict__ bq,
                                              const float* __restrict__ bk,
                                              const float* __restrict__ bv,
                                              unsigned short* __restrict__ Qb,
                                              unsigned short* __restrict__ Kb,
                                              unsigned short* __restrict__ Vt) {
    int tid = threadIdx.x, wid = tid >> 6, lane = tid & 63;
    int l16 = lane & 15, quad = lane >> 4;
    int m0 = blockIdx.x * 64 + wid * 16;
    int sel = blockIdx.y;                 // 0..5
    int mat = sel >> 1;
    int cf0 = (sel & 1) * 5;

    const unsigned short* wsrc = (mat == 0) ? wqb : (mat == 1) ? wkb : wvb;
    const float* bias          = (mat == 0) ? bq  : (mat == 1) ? bk  : bv;
    unsigned short* outp       = (mat == 0) ? Qb  : Kb;

    short8 a[5];
    const unsigned short* arow = xn + (size_t)(m0 + l16) * E_ + quad * 8;
    #pragma unroll
    for (int kc = 0; kc < 5; ++kc) a[kc] = *(const short8*)(arow + kc * 32);

    #pragma unroll
    for (int c = 0; c < 5; ++c) {
        int cf = cf0 + c;
        floatx4 acc = {0.f, 0.f, 0.f, 0.f};
        const unsigned short* bp = wsrc + (size_t)(cf * 16 + l16) * E_ + quad * 8;
        #pragma unroll
        for (int kc = 0; kc < 5; ++kc) {
            short8 bf = *(const short8*)(bp + kc * 32);
            acc = __builtin_amdgcn_mfma_f32_16x16x32_bf16(a[kc], bf, acc, 0, 0, 0);
        }
        int col = cf * 16 + l16;
        float bb = bias[col];
        if (mat == 2) {
            // transposed store: Vt[b][e=col][q=p]
            #pragma unroll
            for (int r = 0; r < 4; ++r) {
                int row = m0 + quad * 4 + r;
                int b_ = row >> 5, p = row & 31;
                Vt[(size_t)b_ * D_TRF + col * 32 + p] = f2bf(acc[r] + bb);
            }
        } else {
            size_t o = (size_t)(m0 + quad * 4) * E_ + col;
            #pragma unroll
            for (int r = 0; r < 4; ++r)
                outp[o + (size_t)r * E_] = f2bf(acc[r] + bb);
        }
    }
}

// ---------------------------------------------------------------------------
// K4: MFMA attention v4, 4 waves per b (grid 512 x 256). All waves compute
// S = QK^T redundantly; softmax over p in-reg; wave 0 writes att->LDS;
// waves split the 5 PV e-chunks. PV B-frags = vector loads from Vt
// (B[n=e][k=q] = Vt[e*32+q], q-contiguous) — replaces 8 scalar loads each.
// ---------------------------------------------------------------------------
__global__ __launch_bounds__(256) void k_attn4(const unsigned short* __restrict__ Q,
                                               const unsigned short* __restrict__ K,
                                               const unsigned short* __restrict__ Vt,
                                               const float* __restrict__ cl,
                                               const float* __restrict__ bt_gain,
                                               const float* __restrict__ bt_bias,
                                               float* __restrict__ h,
                                               unsigned short* __restrict__ x2b) {
    int b = blockIdx.x;
    int tid = threadIdx.x, wid = tid >> 6, lane = tid & 63;
    int l32 = lane & 31, hi = lane >> 5;
    __shared__ __align__(16) unsigned short Satt[32 * 40];   // row stride 40 bf16

    const unsigned short* Qg = Q + (size_t)b * D_TRF;
    const unsigned short* Kg = K + (size_t)b * D_TRF;
    const unsigned short* Vg = Vt + (size_t)b * D_TRF;

    // ---- S = Q K^T (redundant per wave) ----
    floatx16 S = {0.f, 0.f, 0.f, 0.f, 0.f, 0.f, 0.f, 0.f,
                  0.f, 0.f, 0.f, 0.f, 0.f, 0.f, 0.f, 0.f};
    #pragma unroll
    for (int kc = 0; kc < 10; ++kc) {
        int e0 = kc * 16;
        short8 aq = *(const short8*)(Qg + l32 * E_ + e0 + hi * 8);
        short8 bk = *(const short8*)(Kg + l32 * E_ + e0 + hi * 8);
        S = __builtin_amdgcn_mfma_f32_32x32x16_bf16(aq, bk, S, 0, 0, 0);
    }

    // ---- softmax over p (C-layout rows): in-lane 16 regs + shfl_xor(32) ----
    float mx = -1e30f;
    #pragma unroll
    for (int r = 0; r < 16; ++r) { S[r] *= INV_SCALE; mx = fmaxf(mx, S[r]); }
    mx = fmaxf(mx, __shfl_xor(mx, 32));
    float ex[16];
    float sum = 0.f;
    #pragma unroll
    for (int r = 0; r < 16; ++r) { ex[r] = expf(S[r] - mx); sum += ex[r]; }
    sum += __shfl_xor(sum, 32);
    float inv = 1.f / sum;

    // ---- att -> LDS [p][q] bf16 (wave 0 only) ----
    if (wid == 0) {
        #pragma unroll
        for (int r = 0; r < 16; ++r) {
            int p = (r & 3) + 8 * (r >> 2) + 4 * hi;
            Satt[p * 40 + l32] = f2bf(ex[r] * inv);
        }
    }
    __syncthreads();

    // ---- A-frags for PV ----
    short8 a0 = *(const short8*)(&Satt[l32 * 40 + hi * 8]);
    short8 a1 = *(const short8*)(&Satt[l32 * 40 + 16 + hi * 8]);

    const float* clr = cl + (size_t)b * D_TRF;
    float gg = bt_gain[0], bb2 = bt_bias[0];

    for (int t = wid; t < 5; t += 4) {
        int e0 = t * 32;
        short8 b0 = *(const short8*)(Vg + (e0 + l32) * 32 + hi * 8);
        short8 b1 = *(const short8*)(Vg + (e0 + l32) * 32 + 16 + hi * 8);
        floatx16 acc = {0.f, 0.f, 0.f, 0.f, 0.f, 0.f, 0.f, 0.f,
                        0.f, 0.f, 0.f, 0.f, 0.f, 0.f, 0.f, 0.f};
        acc = __builtin_amdgcn_mfma_f32_32x32x16_bf16(a0, b0, acc, 0, 0, 0);
        acc = __builtin_amdgcn_mfma_f32_32x32x16_bf16(a1, b1, acc, 0, 0, 0);
        #pragma unroll
        for (int r = 0; r < 16; ++r) {
            int p = (r & 3) + 8 * (r >> 2) + 4 * hi;
            int idx = p * E_ + e0 + l32;
            float hv = acc[r] + clr[idx];
            h[(size_t)b * D_TRF + idx] = hv;
            x2b[(size_t)b * D_TRF + idx] = f2bf(hv * gg + bb2);
        }
    }
}

// ---------------------------------------------------------------------------
// K5: Better_Transformer via MFMA, register B-frags from global (no LDS).
// ---------------------------------------------------------------------------
__global__ __launch_bounds__(256) void k_bt3(const unsigned short* __restrict__ x2b,
                                             const unsigned short* __restrict__ wtb,
                                             const float* __restrict__ bt_b,
                                             const float* __restrict__ sup_g,
                                             const float* __restrict__ sup_b,
                                             const float* __restrict__ h,
                                             unsigned short* __restrict__ yb) {
    int tid = threadIdx.x, wid = tid >> 6, lane = tid & 63;
    int l16 = lane & 15, quad = lane >> 4;
    int m0 = blockIdx.x * 64 + wid * 16;
    int cf0 = blockIdx.y * 5;

    short8 a[5];
    const unsigned short* arow = x2b + (size_t)(m0 + l16) * E_ + quad * 8;
    #pragma unroll
    for (int kc = 0; kc < 5; ++kc) a[kc] = *(const short8*)(arow + kc * 32);

    #pragma unroll
    for (int c = 0; c < 5; ++c) {
        int cf = cf0 + c;
        floatx4 acc = {0.f, 0.f, 0.f, 0.f};
        const unsigned short* bp = wtb + (size_t)(cf * 16 + l16) * E_ + quad * 8;
        #pragma unroll
        for (int kc = 0; kc < 5; ++kc) {
            short8 bf = *(const short8*)(bp + kc * 32);
            acc = __builtin_amdgcn_mfma_f32_16x16x32_bf16(a[kc], bf, acc, 0, 0, 0);
        }
        int col = cf * 16 + l16;
        float bb = bt_b[col];
        #pragma unroll
        for (int r = 0; r < 4; ++r) {
            int row = m0 + quad * 4 + r;
            int p = row & 31;
            int i = p * E_ + col;
            float o = acc[r] + bb;
            float sig = 1.f / (1.f + expf(-sup_b[i] * o));
            float y = (sup_g[i] + sig * (1.f - sup_g[i])) * o + h[(size_t)row * E_ + col];
            yb[(size_t)row * E_ + col] = f2bf(y);
        }
    }
}

// ---------------------------------------------------------------------------
// K7: head GEMM v9 — m97-structure restructure. (Round-2 resubmit: Round-2's
// bench was an infra/container failure; kernel audited for OOB/hang — none.)
// v8 (47.9 us) was pipeline-structure-bound: A direct-from-global with a
// depth-1 register ping-pong exposed ~200-400 cy of L2 latency per 6-MFMA
// burst, and the per-half stage->drain->barrier serialized staging against
// compute (MfmaUtil 12%, HBM 16%, all pipes idle; doubling occupancy was
// worth only -2.8 us -> not wave-count-curable).
// v9 = the verified m97 2-phase template: BOTH A and B double-buffered in
// LDS via global_load_lds (16B), next-tile loads issued BEFORE the current
// tile's ds_read+MFMA (loads fly during compute, drained by the barrier's
// implicit vmcnt(0)), one barrier per K-step. Inner loop touches only LDS.
// Tile 128m x 96n, BK=64, 20 K-steps, split-K=4. 4 waves (2x2), per wave
// 64x48 = acc[4][3]: 24 MFMA vs 14 ds_read_b128 per step. Both tiles
// XOR-chunk-swizzled (rule #21: linear LDS dest, inverse-swizzled global
// src, swizzled ds_read). LDS 56 KB -> 2 blocks/CU; grid 512 decoded so
// blocks sharing a B-tile / A-tile land on the same XCD (v8 measured:
// FETCH stayed at B-once).
// ---------------------------------------------------------------------------
__global__ __launch_bounds__(256, 2) void k_lin9(const unsigned short* __restrict__ yb,
                                                 const unsigned short* __restrict__ wb,
                                                 float* __restrict__ pb) {
    __shared__ __align__(16) unsigned short As[2][128 * 64];  // 2 x 16 KB
    __shared__ __align__(16) unsigned short Bs[2][96 * 64];   // 2 x 12 KB

    int bid = blockIdx.x;
    int xcd = bid & 7, j = bid >> 3;
    int nt = xcd * 4 + (j & 3);          // 0..31  (96-col tiles)
    int mt = (j >> 2) & 3;               // 0..3   (128-row tiles)
    int sp = j >> 4;                     // 0..3   (split-K, 1280 each)

    int tid = threadIdx.x, wid = tid >> 6, lane = tid & 63;
    int l16 = lane & 15, quad = lane >> 4;
    int wr = wid >> 1, wc = wid & 1;     // 2x2 wave grid

    const size_t aRow0 = (size_t)(mt * 128) * D_TRF;
    const size_t bRow0 = (size_t)(nt * 96) * D_TRF;
    const int k0 = sp * 1280;

    floatx4 acc[4][3];
    #pragma unroll
    for (int fi = 0; fi < 4; ++fi)
        #pragma unroll
        for (int fj = 0; fj < 3; ++fj) acc[fi][fj] = (floatx4){0.f, 0.f, 0.f, 0.f};

    // precomputed swizzled ds-read offsets (in shorts)
    int aOff[4][2], bOff[3][2];
    #pragma unroll
    for (int fi = 0; fi < 4; ++fi) {
        int row = wr * 64 + fi * 16 + l16;
        #pragma unroll
        for (int kk = 0; kk < 2; ++kk)
            aOff[fi][kk] = row * 64 + (((quad + kk * 4) ^ (row & 7)) * 8);
    }
    #pragma unroll
    for (int fj = 0; fj < 3; ++fj) {
        int row = wc * 48 + fj * 16 + l16;
        #pragma unroll
        for (int kk = 0; kk < 2; ++kk)
            bOff[fj][kk] = row * 64 + (((quad + kk * 4) ^ (row & 7)) * 8);
    }

    // stage tile t into buffer buf: A = 1024 16B-chunks, B = 768 chunks.
    // LDS dest is linear (base + lane*16); global src carries the XOR swizzle.
#define STAGE9(buf, t)                                                          \
    do {                                                                        \
        int kh_ = k0 + (t) * 64;                                                \
        _Pragma("unroll")                                                       \
        for (int i_ = 0; i_ < 4; ++i_) {                                        \
            int u_ = i_ * 256 + tid;                                            \
            int row_ = u_ >> 3, c_ = u_ & 7;                                    \
            load_lds16(yb + aRow0 + (size_t)row_ * D_TRF + kh_ +                \
                           ((c_ ^ (row_ & 7)) * 8),                             \
                       (char*)(&As[buf][0]) + (size_t)u_ * 16);                 \
        }                                                                       \
        _Pragma("unroll")                                                       \
        for (int i_ = 0; i_ < 3; ++i_) {                                        \
            int u_ = i_ * 256 + tid;                                            \
            int row_ = u_ >> 3, c_ = u_ & 7;                                    \
            load_lds16(wb + bRow0 + (size_t)row_ * D_TRF + kh_ +                \
                           ((c_ ^ (row_ & 7)) * 8),                             \
                       (char*)(&Bs[buf][0]) + (size_t)u_ * 16);                 \
        }                                                                       \
    } while (0)

    STAGE9(0, 0);
    __syncthreads();                         // implicit vmcnt(0): tile 0 ready

    for (int t = 0; t < 20; ++t) {
        int cur = t & 1;
        if (t < 19) STAGE9(cur ^ 1, t + 1);  // issue next tile, flies during compute

        const unsigned short* Ab = &As[cur][0];
        const unsigned short* Bb = &Bs[cur][0];
        short8 af[4][2], bfr[3][2];
        #pragma unroll
        for (int fi = 0; fi < 4; ++fi)
            #pragma unroll
            for (int kk = 0; kk < 2; ++kk)
                af[fi][kk] = *(const short8*)(Ab + aOff[fi][kk]);
        #pragma unroll
        for (int fj = 0; fj < 3; ++fj)
            #pragma unroll
            for (int kk = 0; kk < 2; ++kk)
                bfr[fj][kk] = *(const short8*)(Bb + bOff[fj][kk]);

        #pragma unroll
        for (int kk = 0; kk < 2; ++kk)
            #pragma unroll
            for (int fi = 0; fi < 4; ++fi)
                #pragma unroll
                for (int fj = 0; fj < 3; ++fj)
                    acc[fi][fj] = __builtin_amdgcn_mfma_f32_16x16x32_bf16(
                        af[fi][kk], bfr[fj][kk], acc[fi][fj], 0, 0, 0);

        __syncthreads();   // drains vmcnt(0) (next tile landed) + guards buf reuse
    }
#undef STAGE9

    // epilogue: coalesced partial stores
    #pragma unroll
    for (int fi = 0; fi < 4; ++fi) {
        int row = mt * 128 + wr * 64 + fi * 16 + quad * 4;
        #pragma unroll
        for (int fj = 0; fj < 3; ++fj) {
            int col = nt * 96 + wc * 48 + fj * 16 + l16;
            #pragma unroll
            for (int r = 0; r < 4; ++r)
                pb[((size_t)(sp * 512 + row + r)) * 3072 + col] = acc[fi][fj][r];
        }
    }
}

// ---------------------------------------------------------------------------
// K8: reduce 4 split-K partials + bias/gain -> out [512,3000]
// ---------------------------------------------------------------------------
__global__ __launch_bounds__(256) void k_red(const float* __restrict__ pb,
                                             const float* __restrict__ lin_b,
                                             const float* __restrict__ out_gain,
                                             const float* __restrict__ out_bias,
                                             float* __restrict__ out) {
    int col = blockIdx.x * 256 + threadIdx.x;
    if (col >= D_OUT) return;
    int row = blockIdx.y;
    size_t base = (size_t)row * 3072 + col;
    const size_t stride = (size_t)512 * 3072;
    float s = pb[base] + pb[base + stride] + pb[base + 2 * stride] + pb[base + 3 * stride];
    float g = out_gain[0];
    out[(size_t)row * D_OUT + col] = s * g + lin_b[col] * g + out_bias[0];
}

// ---------------------------------------------------------------------------
// Workspace layout (bytes)
// ---------------------------------------------------------------------------
#define SZ_ROWF ((size_t)B_ * D_TRF * 4)           // 10,485,760
#define SZ_ROWB ((size_t)B_ * D_TRF * 2)           // 5,242,880
#define OFF_CL  ((size_t)0)
#define OFF_H   (OFF_CL + SZ_ROWF)
#define OFF_XN  (OFF_H + SZ_ROWF)                  // xn bf16; reused as x2b
#define OFF_QB  (OFF_XN + SZ_ROWB)
#define OFF_KB  (OFF_QB + SZ_ROWB)
#define OFF_VB  (OFF_KB + SZ_ROWB)                 // holds Vt [b][e][q]
#define OFF_YB  (OFF_VB + SZ_ROWB)
#define OFF_WSM (OFF_YB + SZ_ROWB)                 // 4 x 51200 B
#define OFF_WB  (OFF_WSM + (size_t)4 * E_ * E_ * 2)
// end = OFF_WB + 3072*5120*2 = 78,848,000 bytes
// pb (head-GEMM partials, 4*512*3072*4 = 25,165,824 B) aliases OFF_CL..:
// cl/h/xn are all dead once k_bt3 has run, and 25.2 MB < OFF_QB (26.2 MB).

extern "C" void kernel_launch(void* const* d_in, const int* in_sizes, int n_in,
                              void* d_out, int out_size, void* d_ws, size_t ws_size,
                              hipStream_t stream) {
    const float* x        = (const float*)d_in[0];
    const float* stdv     = (const float*)d_in[1];
    const float* meanv    = (const float*)d_in[2];
    const float* mat      = (const float*)d_in[3];
    const float* ln_g     = (const float*)d_in[4];
    const float* ln_b     = (const float*)d_in[5];
    const float* wq       = (const float*)d_in[6];
    const float* bq       = (const float*)d_in[7];
    const float* wk       = (const float*)d_in[8];
    const float* bk       = (const float*)d_in[9];
    const float* wv       = (const float*)d_in[10];
    const float* bv       = (const float*)d_in[11];
    const float* bt_w     = (const float*)d_in[12];
    const float* bt_b     = (const float*)d_in[13];
    const float* bt_gain  = (const float*)d_in[14];
    const float* bt_bias  = (const float*)d_in[15];
    const float* sup_g    = (const float*)d_in[16];
    const float* sup_b    = (const float*)d_in[17];
    const float* lin_w    = (const float*)d_in[18];
    const float* lin_b    = (const float*)d_in[19];
    const float* out_gain = (const float*)d_in[20];
    const float* out_bias = (const float*)d_in[21];

    char* ws = (char*)d_ws;
    float* cl = (float*)(ws + OFF_CL);
    float* h  = (float*)(ws + OFF_H);
    unsigned short* xn  = (unsigned short*)(ws + OFF_XN);
    unsigned short* x2b = xn;   // xn dead after k_qkv3
    unsigned short* Qb  = (unsigned short*)(ws + OFF_QB);
    unsigned short* Kb  = (unsigned short*)(ws + OFF_KB);
    unsigned short* Vt  = (unsigned short*)(ws + OFF_VB);
    unsigned short* yb  = (unsigned short*)(ws + OFF_YB);
    unsigned short* wqb = (unsigned short*)(ws + OFF_WSM);
    unsigned short* wkb = wqb + E_ * E_;
    unsigned short* wvb = wkb + E_ * E_;
    unsigned short* wtb = wvb + E_ * E_;
    unsigned short* wb  = (unsigned short*)(ws + OFF_WB);
    float* pb = (float*)(ws + OFF_CL);   // aliases cl/h/xn (dead by k_lin9)
    float* out = (float*)d_out;

    k_castw<<<15360, 256, 0, stream>>>(lin_w, wb);
    k_cast_small<<<100, 256, 0, stream>>>(wq, wk, wv, bt_w, wqb, wkb, wvb, wtb);
    k_cl<<<dim3(64, 4), 256, 0, stream>>>(x, stdv, meanv, mat, cl);
    k_ln<<<512, 256, 0, stream>>>(cl, ln_g, ln_b, xn);
    k_qkv3<<<dim3(256, 6), 256, 0, stream>>>(xn, wqb, wkb, wvb, bq, bk, bv, Qb, Kb, Vt);
    k_attn4<<<512, 256, 0, stream>>>(Qb, Kb, Vt, cl, bt_gain, bt_bias, h, x2b);
    k_bt3<<<dim3(256, 2), 256, 0, stream>>>(x2b, wtb, bt_b, sup_g, sup_b, h, yb);
    k_lin9<<<512, 256, 0, stream>>>(yb, wb, pb);
    k_red<<<dim3(12, 512), 256, 0, stream>>>(pb, lin_b, out_gain, out_bias, out);
}

// Round 4
// 267.331 us; speedup vs baseline: 1.0763x; 1.0342x over previous
//
#include <hip/hip_runtime.h>

// Problem constants
#define B_    512
#define D_TRF 5120
#define P_    32
#define E_    160
#define D_OUT 3000
#define PAD_  61
#define D_CL  4998
#define INV_SCALE 0.07905694150420949f   // 1/sqrt(160)
#define N_PAD 3072          // lin_w rows padded (64 tiles of 48 / 32 tiles of 96)

typedef __attribute__((ext_vector_type(4))) float floatx4;
typedef __attribute__((ext_vector_type(16))) float floatx16;
typedef __attribute__((ext_vector_type(8))) short short8;

static __device__ __forceinline__ unsigned short f2bf(float f) {
    unsigned int u = __float_as_uint(f);
    unsigned int r = (u + 0x7fffu + ((u >> 16) & 1u)) >> 16;
    return (unsigned short)r;
}
static __device__ __forceinline__ float bf2f(unsigned short u) {
    return __uint_as_float(((unsigned int)u) << 16);
}
static __device__ __forceinline__ void load_lds16(const void* g, void* lds) {
    __builtin_amdgcn_global_load_lds(
        (const __attribute__((address_space(1))) unsigned int*)g,
        (__attribute__((address_space(3))) unsigned int*)lds, 16, 0, 0);
}

// ---------------------------------------------------------------------------
// K0: cast lin_w [3000,5120] f32 -> [3072,5120] bf16 (pad rows zeroed)
// ---------------------------------------------------------------------------
__global__ __launch_bounds__(256) void k_castw(const float* __restrict__ w,
                                               unsigned short* __restrict__ wb) {
    size_t i4 = ((size_t)blockIdx.x * 256 + threadIdx.x) * 4;
    size_t o = i4 / D_TRF;
    ushort4 s;
    if (o < D_OUT) {
        float4 v = *(const float4*)(w + i4);
        s.x = f2bf(v.x); s.y = f2bf(v.y); s.z = f2bf(v.z); s.w = f2bf(v.w);
    } else {
        s.x = s.y = s.z = s.w = 0;
    }
    *(ushort4*)(wb + i4) = s;
}

// ---------------------------------------------------------------------------
// K0b: cast wq/wk/wv ([f][e], already B-operand layout) to bf16;
//      transpose bt_w -> wtb[f][e] = bt_w[e][f].
// ---------------------------------------------------------------------------
__global__ __launch_bounds__(256) void k_cast_small(const float* __restrict__ wq,
                                                    const float* __restrict__ wk,
                                                    const float* __restrict__ wv,
                                                    const float* __restrict__ btw,
                                                    unsigned short* __restrict__ wqb,
                                                    unsigned short* __restrict__ wkb,
                                                    unsigned short* __restrict__ wvb,
                                                    unsigned short* __restrict__ wtb) {
    int idx = blockIdx.x * 256 + threadIdx.x;   // < 25600
    wqb[idx] = f2bf(wq[idx]);
    wkb[idx] = f2bf(wk[idx]);
    wvb[idx] = f2bf(wv[idx]);
    int f = idx / E_, e = idx - f * E_;
    wtb[idx] = f2bf(btw[(size_t)e * E_ + f]);
}

// ---------------------------------------------------------------------------
// K1: cl = (x*std+mean) @ mat, with 61-zero pad both sides -> [512,5120]
// ---------------------------------------------------------------------------
__global__ __launch_bounds__(256) void k_cl(const float* __restrict__ x,
                                            const float* __restrict__ stdv,
                                            const float* __restrict__ meanv,
                                            const float* __restrict__ mat,
                                            float* __restrict__ cl) {
    int bg = blockIdx.x, jc = blockIdx.y, tid = threadIdx.x;
    __shared__ float t[8 * 64];
    for (int idx = tid; idx < 8 * 64; idx += 256) {
        int i = idx >> 6, k = idx & 63;
        t[idx] = x[(size_t)(bg * 8 + i) * 64 + k] * stdv[k] + meanv[k];
    }
    __syncthreads();

    if (jc == 0) {
        for (int idx = tid; idx < 8 * PAD_; idx += 256) {
            int i = idx / PAD_, jj = idx - i * PAD_;
            cl[(size_t)(bg * 8 + i) * D_TRF + jj] = 0.f;
        }
    } else if (jc == 3) {
        for (int idx = tid; idx < 8 * PAD_; idx += 256) {
            int i = idx / PAD_, jj = idx - i * PAD_;
            cl[(size_t)(bg * 8 + i) * D_TRF + (D_TRF - PAD_) + jj] = 0.f;
        }
    }

    int j0 = jc * 1250;
    int jend = min(D_CL, j0 + 1250);
    for (int j = j0 + tid; j < jend; j += 256) {
        float acc[8] = {};
        #pragma unroll 16
        for (int k = 0; k < 64; ++k) {
            float m = mat[(size_t)k * D_CL + j];
            #pragma unroll
            for (int i = 0; i < 8; ++i) acc[i] += t[i * 64 + k] * m;
        }
        #pragma unroll
        for (int i = 0; i < 8; ++i)
            cl[(size_t)(bg * 8 + i) * D_TRF + PAD_ + j] = acc[i];
    }
}

// ---------------------------------------------------------------------------
// K2: LayerNorm cl row -> xn bf16 [16384,160]. grid = 512 (one b each)
// ---------------------------------------------------------------------------
__global__ __launch_bounds__(256) void k_ln(const float* __restrict__ cl,
                                            const float* __restrict__ ln_g,
                                            const float* __restrict__ ln_b,
                                            unsigned short* __restrict__ xn) {
    int b = blockIdx.x, tid = threadIdx.x;
    __shared__ float redA[4], redB[4];
    __shared__ float sMu, sRstd;
    const float* row = cl + (size_t)b * D_TRF;

    float s = 0.f, s2 = 0.f;
    #pragma unroll
    for (int it = 0; it < 5; ++it) {
        int i4 = (it * 256 + tid) * 4;
        float4 v = *(const float4*)(row + i4);
        s += v.x + v.y + v.z + v.w;
        s2 += v.x * v.x + v.y * v.y + v.z * v.z + v.w * v.w;
    }
    #pragma unroll
    for (int off = 32; off; off >>= 1) {
        s  += __shfl_down(s, off);
        s2 += __shfl_down(s2, off);
    }
    if ((tid & 63) == 0) { redA[tid >> 6] = s; redB[tid >> 6] = s2; }
    __syncthreads();
    if (tid == 0) {
        float S = redA[0] + redA[1] + redA[2] + redA[3];
        float S2 = redB[0] + redB[1] + redB[2] + redB[3];
        float mu = S / (float)D_TRF;
        float var = S2 / (float)D_TRF - mu * mu;
        sMu = mu; sRstd = rsqrtf(var + 1e-5f);
    }
    __syncthreads();
    float mu = sMu, rs = sRstd;
    #pragma unroll
    for (int it = 0; it < 5; ++it) {
        int i4 = (it * 256 + tid) * 4;
        float4 v = *(const float4*)(row + i4);
        float4 g = *(const float4*)(ln_g + i4);
        float4 be = *(const float4*)(ln_b + i4);
        ushort4 o;
        o.x = f2bf((v.x - mu) * rs * g.x + be.x);
        o.y = f2bf((v.y - mu) * rs * g.y + be.y);
        o.z = f2bf((v.z - mu) * rs * g.z + be.z);
        o.w = f2bf((v.w - mu) * rs * g.w + be.w);
        *(ushort4*)(xn + (size_t)b * D_TRF + i4) = o;
    }
}

// ---------------------------------------------------------------------------
// K3: QKV via MFMA, register-resident B-frags loaded straight from global.
// V is stored TRANSPOSED per b: Vt[b*5120 + e*32 + q] (q contiguous) so the
// attention PV B-frags become single 16B vector loads.
// ---------------------------------------------------------------------------
__global__ __launch_bounds__(256) void k_qkv3(const unsigned short* __restrict__ xn,
                                              const unsigned short* __restrict__ wqb,
                                              const unsigned short* __restrict__ wkb,
                                              const unsigned short* __restrict__ wvb,
                                              const float* __restrict__ bq,
                                              const float* __restrict__ bk,
                                              const float* __restrict__ bv,
                                              unsigned short* __restrict__ Qb,
                                              unsigned short* __restrict__ Kb,
                                              unsigned short* __restrict__ Vt) {
    int tid = threadIdx.x, wid = tid >> 6, lane = tid & 63;
    int l16 = lane & 15, quad = lane >> 4;
    int m0 = blockIdx.x * 64 + wid * 16;
    int sel = blockIdx.y;                 // 0..5
    int mat = sel >> 1;
    int cf0 = (sel & 1) * 5;

    const unsigned short* wsrc = (mat == 0) ? wqb : (mat == 1) ? wkb : wvb;
    const float* bias          = (mat == 0) ? bq  : (mat == 1) ? bk  : bv;
    unsigned short* outp       = (mat == 0) ? Qb  : Kb;

    short8 a[5];
    const unsigned short* arow = xn + (size_t)(m0 + l16) * E_ + quad * 8;
    #pragma unroll
    for (int kc = 0; kc < 5; ++kc) a[kc] = *(const short8*)(arow + kc * 32);

    #pragma unroll
    for (int c = 0; c < 5; ++c) {
        int cf = cf0 + c;
        floatx4 acc = {0.f, 0.f, 0.f, 0.f};
        const unsigned short* bp = wsrc + (size_t)(cf * 16 + l16) * E_ + quad * 8;
        #pragma unroll
        for (int kc = 0; kc < 5; ++kc) {
            short8 bf = *(const short8*)(bp + kc * 32);
            acc = __builtin_amdgcn_mfma_f32_16x16x32_bf16(a[kc], bf, acc, 0, 0, 0);
        }
        int col = cf * 16 + l16;
        float bb = bias[col];
        if (mat == 2) {
            // transposed store: Vt[b][e=col][q=p]
            #pragma unroll
            for (int r = 0; r < 4; ++r) {
                int row = m0 + quad * 4 + r;
                int b_ = row >> 5, p = row & 31;
                Vt[(size_t)b_ * D_TRF + col * 32 + p] = f2bf(acc[r] + bb);
            }
        } else {
            size_t o = (size_t)(m0 + quad * 4) * E_ + col;
            #pragma unroll
            for (int r = 0; r < 4; ++r)
                outp[o + (size_t)r * E_] = f2bf(acc[r] + bb);
        }
    }
}

// ---------------------------------------------------------------------------
// K4: MFMA attention v4, 4 waves per b (grid 512 x 256). All waves compute
// S = QK^T redundantly; softmax over p in-reg; wave 0 writes att->LDS;
// waves split the 5 PV e-chunks. PV B-frags = vector loads from Vt
// (B[n=e][k=q] = Vt[e*32+q], q-contiguous) — replaces 8 scalar loads each.
// ---------------------------------------------------------------------------
__global__ __launch_bounds__(256) void k_attn4(const unsigned short* __restrict__ Q,
                                               const unsigned short* __restrict__ K,
                                               const unsigned short* __restrict__ Vt,
                                               const float* __restrict__ cl,
                                               const float* __restrict__ bt_gain,
                                               const float* __restrict__ bt_bias,
                                               float* __restrict__ h,
                                               unsigned short* __restrict__ x2b) {
    int b = blockIdx.x;
    int tid = threadIdx.x, wid = tid >> 6, lane = tid & 63;
    int l32 = lane & 31, hi = lane >> 5;
    __shared__ __align__(16) unsigned short Satt[32 * 40];   // row stride 40 bf16

    const unsigned short* Qg = Q + (size_t)b * D_TRF;
    const unsigned short* Kg = K + (size_t)b * D_TRF;
    const unsigned short* Vg = Vt + (size_t)b * D_TRF;

    // ---- S = Q K^T (redundant per wave) ----
    floatx16 S = {0.f, 0.f, 0.f, 0.f, 0.f, 0.f, 0.f, 0.f,
                  0.f, 0.f, 0.f, 0.f, 0.f, 0.f, 0.f, 0.f};
    #pragma unroll
    for (int kc = 0; kc < 10; ++kc) {
        int e0 = kc * 16;
        short8 aq = *(const short8*)(Qg + l32 * E_ + e0 + hi * 8);
        short8 bk = *(const short8*)(Kg + l32 * E_ + e0 + hi * 8);
        S = __builtin_amdgcn_mfma_f32_32x32x16_bf16(aq, bk, S, 0, 0, 0);
    }

    // ---- softmax over p (C-layout rows): in-lane 16 regs + shfl_xor(32) ----
    float mx = -1e30f;
    #pragma unroll
    for (int r = 0; r < 16; ++r) { S[r] *= INV_SCALE; mx = fmaxf(mx, S[r]); }
    mx = fmaxf(mx, __shfl_xor(mx, 32));
    float ex[16];
    float sum = 0.f;
    #pragma unroll
    for (int r = 0; r < 16; ++r) { ex[r] = expf(S[r] - mx); sum += ex[r]; }
    sum += __shfl_xor(sum, 32);
    float inv = 1.f / sum;

    // ---- att -> LDS [p][q] bf16 (wave 0 only) ----
    if (wid == 0) {
        #pragma unroll
        for (int r = 0; r < 16; ++r) {
            int p = (r & 3) + 8 * (r >> 2) + 4 * hi;
            Satt[p * 40 + l32] = f2bf(ex[r] * inv);
        }
    }
    __syncthreads();

    // ---- A-frags for PV ----
    short8 a0 = *(const short8*)(&Satt[l32 * 40 + hi * 8]);
    short8 a1 = *(const short8*)(&Satt[l32 * 40 + 16 + hi * 8]);

    const float* clr = cl + (size_t)b * D_TRF;
    float gg = bt_gain[0], bb2 = bt_bias[0];

    for (int t = wid; t < 5; t += 4) {
        int e0 = t * 32;
        short8 b0 = *(const short8*)(Vg + (e0 + l32) * 32 + hi * 8);
        short8 b1 = *(const short8*)(Vg + (e0 + l32) * 32 + 16 + hi * 8);
        floatx16 acc = {0.f, 0.f, 0.f, 0.f, 0.f, 0.f, 0.f, 0.f,
                        0.f, 0.f, 0.f, 0.f, 0.f, 0.f, 0.f, 0.f};
        acc = __builtin_amdgcn_mfma_f32_32x32x16_bf16(a0, b0, acc, 0, 0, 0);
        acc = __builtin_amdgcn_mfma_f32_32x32x16_bf16(a1, b1, acc, 0, 0, 0);
        #pragma unroll
        for (int r = 0; r < 16; ++r) {
            int p = (r & 3) + 8 * (r >> 2) + 4 * hi;
            int idx = p * E_ + e0 + l32;
            float hv = acc[r] + clr[idx];
            h[(size_t)b * D_TRF + idx] = hv;
            x2b[(size_t)b * D_TRF + idx] = f2bf(hv * gg + bb2);
        }
    }
}

// ---------------------------------------------------------------------------
// K5: Better_Transformer via MFMA, register B-frags from global (no LDS).
// ---------------------------------------------------------------------------
__global__ __launch_bounds__(256) void k_bt3(const unsigned short* __restrict__ x2b,
                                             const unsigned short* __restrict__ wtb,
                                             const float* __restrict__ bt_b,
                                             const float* __restrict__ sup_g,
                                             const float* __restrict__ sup_b,
                                             const float* __restrict__ h,
                                             unsigned short* __restrict__ yb) {
    int tid = threadIdx.x, wid = tid >> 6, lane = tid & 63;
    int l16 = lane & 15, quad = lane >> 4;
    int m0 = blockIdx.x * 64 + wid * 16;
    int cf0 = blockIdx.y * 5;

    short8 a[5];
    const unsigned short* arow = x2b + (size_t)(m0 + l16) * E_ + quad * 8;
    #pragma unroll
    for (int kc = 0; kc < 5; ++kc) a[kc] = *(const short8*)(arow + kc * 32);

    #pragma unroll
    for (int c = 0; c < 5; ++c) {
        int cf = cf0 + c;
        floatx4 acc = {0.f, 0.f, 0.f, 0.f};
        const unsigned short* bp = wtb + (size_t)(cf * 16 + l16) * E_ + quad * 8;
        #pragma unroll
        for (int kc = 0; kc < 5; ++kc) {
            short8 bf = *(const short8*)(bp + kc * 32);
            acc = __builtin_amdgcn_mfma_f32_16x16x32_bf16(a[kc], bf, acc, 0, 0, 0);
        }
        int col = cf * 16 + l16;
        float bb = bt_b[col];
        #pragma unroll
        for (int r = 0; r < 4; ++r) {
            int row = m0 + quad * 4 + r;
            int p = row & 31;
            int i = p * E_ + col;
            float o = acc[r] + bb;
            float sig = 1.f / (1.f + expf(-sup_b[i] * o));
            float y = (sup_g[i] + sig * (1.f - sup_g[i])) * o + h[(size_t)row * E_ + col];
            yb[(size_t)row * E_ + col] = f2bf(y);
        }
    }
}

// ---------------------------------------------------------------------------
// K7: head GEMM v10 — v9 + counted vmcnt (T4), the one isolated change.
// v9 (~36.6 us inferred: total -11.2 vs v8) removed the register-ping-pong
// stall but kept __syncthreads() per K-step, which compiles to
// s_waitcnt vmcnt(0): it drains the NEXT tile's just-issued loads (~300-700
// cy exposed per step x20). v10 replaces both barriers with raw s_barrier
// and waits vmcnt(7) — the 7 loads of tile t (issued one FULL iteration
// earlier) are done; tile t+1's 7 stay in flight across the barrier
// (m218: counted-vs-drain0 = +38..73%).
// Hazards audited: buf[cur^1] overwritten by iter-t stage was read in iter
// t-1, protected by iter t-1's end (lgkmcnt(0)+barrier); ds_reads are plain
// loads (compiler inserts lgkm waits; rule-18 N/A); "memory" asm beside
// each barrier blocks reordering; stage branch is grid-uniform (no
// divergent barrier); exactly 7 wave-uniform vmem insts per stage so
// vmcnt(7) is well-defined; epilogue stores issue after final vmcnt(0).
// ---------------------------------------------------------------------------
__global__ __launch_bounds__(256, 2) void k_lin10(const unsigned short* __restrict__ yb,
                                                  const unsigned short* __restrict__ wb,
                                                  float* __restrict__ pb) {
    __shared__ __align__(16) unsigned short As[2][128 * 64];  // 2 x 16 KB
    __shared__ __align__(16) unsigned short Bs[2][96 * 64];   // 2 x 12 KB

    int bid = blockIdx.x;
    int xcd = bid & 7, j = bid >> 3;
    int nt = xcd * 4 + (j & 3);          // 0..31  (96-col tiles)
    int mt = (j >> 2) & 3;               // 0..3   (128-row tiles)
    int sp = j >> 4;                     // 0..3   (split-K, 1280 each)

    int tid = threadIdx.x, wid = tid >> 6, lane = tid & 63;
    int l16 = lane & 15, quad = lane >> 4;
    int wr = wid >> 1, wc = wid & 1;     // 2x2 wave grid

    const size_t aRow0 = (size_t)(mt * 128) * D_TRF;
    const size_t bRow0 = (size_t)(nt * 96) * D_TRF;
    const int k0 = sp * 1280;

    floatx4 acc[4][3];
    #pragma unroll
    for (int fi = 0; fi < 4; ++fi)
        #pragma unroll
        for (int fj = 0; fj < 3; ++fj) acc[fi][fj] = (floatx4){0.f, 0.f, 0.f, 0.f};

    // precomputed swizzled ds-read offsets (in shorts)
    int aOff[4][2], bOff[3][2];
    #pragma unroll
    for (int fi = 0; fi < 4; ++fi) {
        int row = wr * 64 + fi * 16 + l16;
        #pragma unroll
        for (int kk = 0; kk < 2; ++kk)
            aOff[fi][kk] = row * 64 + (((quad + kk * 4) ^ (row & 7)) * 8);
    }
    #pragma unroll
    for (int fj = 0; fj < 3; ++fj) {
        int row = wc * 48 + fj * 16 + l16;
        #pragma unroll
        for (int kk = 0; kk < 2; ++kk)
            bOff[fj][kk] = row * 64 + (((quad + kk * 4) ^ (row & 7)) * 8);
    }

    // stage tile t into buffer buf: A = 1024 16B-chunks (4 insts/wave),
    // B = 768 chunks (3 insts/wave) -> exactly 7 vmem insts per wave.
    // LDS dest linear (base + lane*16); global src carries the XOR swizzle.
#define STAGE10(buf, t)                                                         \
    do {                                                                        \
        int kh_ = k0 + (t) * 64;                                                \
        _Pragma("unroll")                                                       \
        for (int i_ = 0; i_ < 4; ++i_) {                                        \
            int u_ = i_ * 256 + tid;                                            \
            int row_ = u_ >> 3, c_ = u_ & 7;                                    \
            load_lds16(yb + aRow0 + (size_t)row_ * D_TRF + kh_ +                \
                           ((c_ ^ (row_ & 7)) * 8),                             \
                       (char*)(&As[buf][0]) + (size_t)u_ * 16);                 \
        }                                                                       \
        _Pragma("unroll")                                                       \
        for (int i_ = 0; i_ < 3; ++i_) {                                        \
            int u_ = i_ * 256 + tid;                                            \
            int row_ = u_ >> 3, c_ = u_ & 7;                                    \
            load_lds16(wb + bRow0 + (size_t)row_ * D_TRF + kh_ +                \
                           ((c_ ^ (row_ & 7)) * 8),                             \
                       (char*)(&Bs[buf][0]) + (size_t)u_ * 16);                 \
        }                                                                       \
    } while (0)

    STAGE10(0, 0);                            // 7 in flight; no wait here

    for (int t = 0; t < 20; ++t) {
        int cur = t & 1;
        if (t < 19) {
            STAGE10(cur ^ 1, t + 1);          // -> 14 in flight
            asm volatile("s_waitcnt vmcnt(7)" ::: "memory");   // tile t landed
        } else {
            asm volatile("s_waitcnt vmcnt(0)" ::: "memory");   // last tile
        }
        __builtin_amdgcn_s_barrier();         // raw: does NOT drain vmcnt

        const unsigned short* Ab = &As[cur][0];
        const unsigned short* Bb = &Bs[cur][0];
        short8 af[4][2], bfr[3][2];
        #pragma unroll
        for (int fi = 0; fi < 4; ++fi)
            #pragma unroll
            for (int kk = 0; kk < 2; ++kk)
                af[fi][kk] = *(const short8*)(Ab + aOff[fi][kk]);
        #pragma unroll
        for (int fj = 0; fj < 3; ++fj)
            #pragma unroll
            for (int kk = 0; kk < 2; ++kk)
                bfr[fj][kk] = *(const short8*)(Bb + bOff[fj][kk]);

        #pragma unroll
        for (int kk = 0; kk < 2; ++kk)
            #pragma unroll
            for (int fi = 0; fi < 4; ++fi)
                #pragma unroll
                for (int fj = 0; fj < 3; ++fj)
                    acc[fi][fj] = __builtin_amdgcn_mfma_f32_16x16x32_bf16(
                        af[fi][kk], bfr[fj][kk], acc[fi][fj], 0, 0, 0);

        asm volatile("s_waitcnt lgkmcnt(0)" ::: "memory");  // all ds_reads done
        __builtin_amdgcn_s_barrier();         // guards buf overwrite next iter
    }
#undef STAGE10

    // epilogue: coalesced partial stores
    #pragma unroll
    for (int fi = 0; fi < 4; ++fi) {
        int row = mt * 128 + wr * 64 + fi * 16 + quad * 4;
        #pragma unroll
        for (int fj = 0; fj < 3; ++fj) {
            int col = nt * 96 + wc * 48 + fj * 16 + l16;
            #pragma unroll
            for (int r = 0; r < 4; ++r)
                pb[((size_t)(sp * 512 + row + r)) * 3072 + col] = acc[fi][fj][r];
        }
    }
}

// ---------------------------------------------------------------------------
// K8: reduce 4 split-K partials + bias/gain -> out [512,3000]
// ---------------------------------------------------------------------------
__global__ __launch_bounds__(256) void k_red(const float* __restrict__ pb,
                                             const float* __restrict__ lin_b,
                                             const float* __restrict__ out_gain,
                                             const float* __restrict__ out_bias,
                                             float* __restrict__ out) {
    int col = blockIdx.x * 256 + threadIdx.x;
    if (col >= D_OUT) return;
    int row = blockIdx.y;
    size_t base = (size_t)row * 3072 + col;
    const size_t stride = (size_t)512 * 3072;
    float s = pb[base] + pb[base + stride] + pb[base + 2 * stride] + pb[base + 3 * stride];
    float g = out_gain[0];
    out[(size_t)row * D_OUT + col] = s * g + lin_b[col] * g + out_bias[0];
}

// ---------------------------------------------------------------------------
// Workspace layout (bytes)
// ---------------------------------------------------------------------------
#define SZ_ROWF ((size_t)B_ * D_TRF * 4)           // 10,485,760
#define SZ_ROWB ((size_t)B_ * D_TRF * 2)           // 5,242,880
#define OFF_CL  ((size_t)0)
#define OFF_H   (OFF_CL + SZ_ROWF)
#define OFF_XN  (OFF_H + SZ_ROWF)                  // xn bf16; reused as x2b
#define OFF_QB  (OFF_XN + SZ_ROWB)
#define OFF_KB  (OFF_QB + SZ_ROWB)
#define OFF_VB  (OFF_KB + SZ_ROWB)                 // holds Vt [b][e][q]
#define OFF_YB  (OFF_VB + SZ_ROWB)
#define OFF_WSM (OFF_YB + SZ_ROWB)                 // 4 x 51200 B
#define OFF_WB  (OFF_WSM + (size_t)4 * E_ * E_ * 2)
// end = OFF_WB + 3072*5120*2 = 78,848,000 bytes
// pb (head-GEMM partials, 4*512*3072*4 = 25,165,824 B) aliases OFF_CL..:
// cl/h/xn are all dead once k_bt3 has run, and 25.2 MB < OFF_QB (26.2 MB).

extern "C" void kernel_launch(void* const* d_in, const int* in_sizes, int n_in,
                              void* d_out, int out_size, void* d_ws, size_t ws_size,
                              hipStream_t stream) {
    const float* x        = (const float*)d_in[0];
    const float* stdv     = (const float*)d_in[1];
    const float* meanv    = (const float*)d_in[2];
    const float* mat      = (const float*)d_in[3];
    const float* ln_g     = (const float*)d_in[4];
    const float* ln_b     = (const float*)d_in[5];
    const float* wq       = (const float*)d_in[6];
    const float* bq       = (const float*)d_in[7];
    const float* wk       = (const float*)d_in[8];
    const float* bk       = (const float*)d_in[9];
    const float* wv       = (const float*)d_in[10];
    const float* bv       = (const float*)d_in[11];
    const float* bt_w     = (const float*)d_in[12];
    const float* bt_b     = (const float*)d_in[13];
    const float* bt_gain  = (const float*)d_in[14];
    const float* bt_bias  = (const float*)d_in[15];
    const float* sup_g    = (const float*)d_in[16];
    const float* sup_b    = (const float*)d_in[17];
    const float* lin_w    = (const float*)d_in[18];
    const float* lin_b    = (const float*)d_in[19];
    const float* out_gain = (const float*)d_in[20];
    const float* out_bias = (const float*)d_in[21];

    char* ws = (char*)d_ws;
    float* cl = (float*)(ws + OFF_CL);
    float* h  = (float*)(ws + OFF_H);
    unsigned short* xn  = (unsigned short*)(ws + OFF_XN);
    unsigned short* x2b = xn;   // xn dead after k_qkv3
    unsigned short* Qb  = (unsigned short*)(ws + OFF_QB);
    unsigned short* Kb  = (unsigned short*)(ws + OFF_KB);
    unsigned short* Vt  = (unsigned short*)(ws + OFF_VB);
    unsigned short* yb  = (unsigned short*)(ws + OFF_YB);
    unsigned short* wqb = (unsigned short*)(ws + OFF_WSM);
    unsigned short* wkb = wqb + E_ * E_;
    unsigned short* wvb = wkb + E_ * E_;
    unsigned short* wtb = wvb + E_ * E_;
    unsigned short* wb  = (unsigned short*)(ws + OFF_WB);
    float* pb = (float*)(ws + OFF_CL);   // aliases cl/h/xn (dead by k_lin10)
    float* out = (float*)d_out;

    k_castw<<<15360, 256, 0, stream>>>(lin_w, wb);
    k_cast_small<<<100, 256, 0, stream>>>(wq, wk, wv, bt_w, wqb, wkb, wvb, wtb);
    k_cl<<<dim3(64, 4), 256, 0, stream>>>(x, stdv, meanv, mat, cl);
    k_ln<<<512, 256, 0, stream>>>(cl, ln_g, ln_b, xn);
    k_qkv3<<<dim3(256, 6), 256, 0, stream>>>(xn, wqb, wkb, wvb, bq, bk, bv, Qb, Kb, Vt);
    k_attn4<<<512, 256, 0, stream>>>(Qb, Kb, Vt, cl, bt_gain, bt_bias, h, x2b);
    k_bt3<<<dim3(256, 2), 256, 0, stream>>>(x2b, wtb, bt_b, sup_g, sup_b, h, yb);
    k_lin10<<<512, 256, 0, stream>>>(yb, wb, pb);
    k_red<<<dim3(12, 512), 256, 0, stream>>>(pb, lin_b, out_gain, out_bias, out);
}

// Round 5
// 245.559 us; speedup vs baseline: 1.1718x; 1.0887x over previous
//
#include <hip/hip_runtime.h>

// Problem constants
#define B_    512
#define D_TRF 5120
#define P_    32
#define E_    160
#define D_OUT 3000
#define PAD_  61
#define D_CL  4998
#define INV_SCALE 0.07905694150420949f   // 1/sqrt(160)
#define N_PAD 3072          // lin_w rows padded (32 tiles of 96)

typedef __attribute__((ext_vector_type(4))) float floatx4;
typedef __attribute__((ext_vector_type(16))) float floatx16;
typedef __attribute__((ext_vector_type(8))) short short8;

static __device__ __forceinline__ unsigned short f2bf(float f) {
    unsigned int u = __float_as_uint(f);
    unsigned int r = (u + 0x7fffu + ((u >> 16) & 1u)) >> 16;
    return (unsigned short)r;
}
static __device__ __forceinline__ float bf2f(unsigned short u) {
    return __uint_as_float(((unsigned int)u) << 16);
}
static __device__ __forceinline__ void load_lds16(const void* g, void* lds) {
    __builtin_amdgcn_global_load_lds(
        (const __attribute__((address_space(1))) unsigned int*)g,
        (__attribute__((address_space(3))) unsigned int*)lds, 16, 0, 0);
}

// ---------------------------------------------------------------------------
// K0: cast lin_w [3000,5120] f32 -> [3072,5120] bf16 (pad rows zeroed)
// ---------------------------------------------------------------------------
__global__ __launch_bounds__(256) void k_castw(const float* __restrict__ w,
                                               unsigned short* __restrict__ wb) {
    size_t i4 = ((size_t)blockIdx.x * 256 + threadIdx.x) * 4;
    size_t o = i4 / D_TRF;
    ushort4 s;
    if (o < D_OUT) {
        float4 v = *(const float4*)(w + i4);
        s.x = f2bf(v.x); s.y = f2bf(v.y); s.z = f2bf(v.z); s.w = f2bf(v.w);
    } else {
        s.x = s.y = s.z = s.w = 0;
    }
    *(ushort4*)(wb + i4) = s;
}

// ---------------------------------------------------------------------------
// K0b: cast wq/wk/wv ([f][e], already B-operand layout) to bf16;
//      transpose bt_w -> wtb[f][e] = bt_w[e][f].
// ---------------------------------------------------------------------------
__global__ __launch_bounds__(256) void k_cast_small(const float* __restrict__ wq,
                                                    const float* __restrict__ wk,
                                                    const float* __restrict__ wv,
                                                    const float* __restrict__ btw,
                                                    unsigned short* __restrict__ wqb,
                                                    unsigned short* __restrict__ wkb,
                                                    unsigned short* __restrict__ wvb,
                                                    unsigned short* __restrict__ wtb) {
    int idx = blockIdx.x * 256 + threadIdx.x;   // < 25600
    wqb[idx] = f2bf(wq[idx]);
    wkb[idx] = f2bf(wk[idx]);
    wvb[idx] = f2bf(wv[idx]);
    int f = idx / E_, e = idx - f * E_;
    wtb[idx] = f2bf(btw[(size_t)e * E_ + f]);
}

// ---------------------------------------------------------------------------
// K1: cl = (x*std+mean) @ mat, with 61-zero pad both sides -> [512,5120]
// ---------------------------------------------------------------------------
__global__ __launch_bounds__(256) void k_cl(const float* __restrict__ x,
                                            const float* __restrict__ stdv,
                                            const float* __restrict__ meanv,
                                            const float* __restrict__ mat,
                                            float* __restrict__ cl) {
    int bg = blockIdx.x, jc = blockIdx.y, tid = threadIdx.x;
    __shared__ float t[8 * 64];
    for (int idx = tid; idx < 8 * 64; idx += 256) {
        int i = idx >> 6, k = idx & 63;
        t[idx] = x[(size_t)(bg * 8 + i) * 64 + k] * stdv[k] + meanv[k];
    }
    __syncthreads();

    if (jc == 0) {
        for (int idx = tid; idx < 8 * PAD_; idx += 256) {
            int i = idx / PAD_, jj = idx - i * PAD_;
            cl[(size_t)(bg * 8 + i) * D_TRF + jj] = 0.f;
        }
    } else if (jc == 3) {
        for (int idx = tid; idx < 8 * PAD_; idx += 256) {
            int i = idx / PAD_, jj = idx - i * PAD_;
            cl[(size_t)(bg * 8 + i) * D_TRF + (D_TRF - PAD_) + jj] = 0.f;
        }
    }

    int j0 = jc * 1250;
    int jend = min(D_CL, j0 + 1250);
    for (int j = j0 + tid; j < jend; j += 256) {
        float acc[8] = {};
        #pragma unroll 16
        for (int k = 0; k < 64; ++k) {
            float m = mat[(size_t)k * D_CL + j];
            #pragma unroll
            for (int i = 0; i < 8; ++i) acc[i] += t[i * 64 + k] * m;
        }
        #pragma unroll
        for (int i = 0; i < 8; ++i)
            cl[(size_t)(bg * 8 + i) * D_TRF + PAD_ + j] = acc[i];
    }
}

// ---------------------------------------------------------------------------
// K2: LayerNorm cl row -> xn bf16 [16384,160]. grid = 512 (one b each)
// ---------------------------------------------------------------------------
__global__ __launch_bounds__(256) void k_ln(const float* __restrict__ cl,
                                            const float* __restrict__ ln_g,
                                            const float* __restrict__ ln_b,
                                            unsigned short* __restrict__ xn) {
    int b = blockIdx.x, tid = threadIdx.x;
    __shared__ float redA[4], redB[4];
    __shared__ float sMu, sRstd;
    const float* row = cl + (size_t)b * D_TRF;

    float s = 0.f, s2 = 0.f;
    #pragma unroll
    for (int it = 0; it < 5; ++it) {
        int i4 = (it * 256 + tid) * 4;
        float4 v = *(const float4*)(row + i4);
        s += v.x + v.y + v.z + v.w;
        s2 += v.x * v.x + v.y * v.y + v.z * v.z + v.w * v.w;
    }
    #pragma unroll
    for (int off = 32; off; off >>= 1) {
        s  += __shfl_down(s, off);
        s2 += __shfl_down(s2, off);
    }
    if ((tid & 63) == 0) { redA[tid >> 6] = s; redB[tid >> 6] = s2; }
    __syncthreads();
    if (tid == 0) {
        float S = redA[0] + redA[1] + redA[2] + redA[3];
        float S2 = redB[0] + redB[1] + redB[2] + redB[3];
        float mu = S / (float)D_TRF;
        float var = S2 / (float)D_TRF - mu * mu;
        sMu = mu; sRstd = rsqrtf(var + 1e-5f);
    }
    __syncthreads();
    float mu = sMu, rs = sRstd;
    #pragma unroll
    for (int it = 0; it < 5; ++it) {
        int i4 = (it * 256 + tid) * 4;
        float4 v = *(const float4*)(row + i4);
        float4 g = *(const float4*)(ln_g + i4);
        float4 be = *(const float4*)(ln_b + i4);
        ushort4 o;
        o.x = f2bf((v.x - mu) * rs * g.x + be.x);
        o.y = f2bf((v.y - mu) * rs * g.y + be.y);
        o.z = f2bf((v.z - mu) * rs * g.z + be.z);
        o.w = f2bf((v.w - mu) * rs * g.w + be.w);
        *(ushort4*)(xn + (size_t)b * D_TRF + i4) = o;
    }
}

// ---------------------------------------------------------------------------
// K3456: fused QKV + attention + Better_Transformer, one block per b.
// Eliminates Qb/Kb/Vt/h/x2b global round-trips (~63 MB) and 2 launches.
// All MFMA mappings are the session-verified attn4 patterns:
//   C[p][f] = sum_e A[p][e] W[f][e] via mfma_32x32x16(A-row=l32, B-row=l32),
//   C map p=(r&3)+8*(r>>2)+4*hi, col=l32.
// LDS (47.6 KB, all b128 rows 16B-aligned):
//   region1: Q[32][168] + K[32][168] bf16 (21504 B) -> reused as h[32][168] f32
//   Vt[160][40] bf16 (12800 B)   att[32][40] bf16 (2560 B)
//   region4: xn[32][168] bf16 -> reused as x2[32][168] bf16 (10752 B)
// ---------------------------------------------------------------------------
__global__ __launch_bounds__(256) void k_qab(const unsigned short* __restrict__ xn,
                                             const float* __restrict__ cl,
                                             const unsigned short* __restrict__ wqb,
                                             const unsigned short* __restrict__ wkb,
                                             const unsigned short* __restrict__ wvb,
                                             const unsigned short* __restrict__ wtb,
                                             const float* __restrict__ bq,
                                             const float* __restrict__ bk,
                                             const float* __restrict__ bv,
                                             const float* __restrict__ bt_b,
                                             const float* __restrict__ bt_gain,
                                             const float* __restrict__ bt_bias,
                                             const float* __restrict__ sup_g,
                                             const float* __restrict__ sup_b,
                                             unsigned short* __restrict__ yb) {
    __shared__ __align__(16) char smem[47616];
    unsigned short* Qlds = (unsigned short*)smem;                     // [32][168]
    unsigned short* Klds = Qlds + 32 * 168;                           // [32][168]
    float*          hlds = (float*)smem;                              // [32][168] aliases Q,K
    unsigned short* Vtl  = (unsigned short*)(smem + 21504);           // [160][40]
    unsigned short* Satt = (unsigned short*)(smem + 21504 + 12800);   // [32][40]
    unsigned short* xnl  = (unsigned short*)(smem + 21504 + 12800 + 2560); // [32][168] -> x2

    int b = blockIdx.x;
    int tid = threadIdx.x, wid = tid >> 6, lane = tid & 63;
    int l32 = lane & 31, hi = lane >> 5;

    // ---- stage xn[b] (32x160 bf16) -> LDS padded rows ----
    const unsigned short* xg = xn + (size_t)b * D_TRF;
    #pragma unroll
    for (int it = 0; it < 3; ++it) {
        int u = it * 256 + tid;
        if (u < 640) {
            int row = u / 20, c = u - row * 20;
            *(short8*)(xnl + row * 168 + c * 8) = *(const short8*)(xg + row * 160 + c * 8);
        }
    }
    __syncthreads();

    // ---- QKV: 15 32x32 tiles (3 mats x 5 col-tiles), waves strided ----
    for (int tc = wid; tc < 15; tc += 4) {
        int mat = tc / 5, f0 = (tc - mat * 5) * 32;
        const unsigned short* wsrc = (mat == 0) ? wqb : (mat == 1) ? wkb : wvb;
        const float* bias          = (mat == 0) ? bq  : (mat == 1) ? bk  : bv;
        floatx16 acc = {0.f, 0.f, 0.f, 0.f, 0.f, 0.f, 0.f, 0.f,
                        0.f, 0.f, 0.f, 0.f, 0.f, 0.f, 0.f, 0.f};
        #pragma unroll
        for (int kc = 0; kc < 10; ++kc) {
            int e0 = kc * 16;
            short8 af = *(const short8*)(xnl + l32 * 168 + e0 + hi * 8);
            short8 bf = *(const short8*)(wsrc + (size_t)(f0 + l32) * E_ + e0 + hi * 8);
            acc = __builtin_amdgcn_mfma_f32_32x32x16_bf16(af, bf, acc, 0, 0, 0);
        }
        int f = f0 + l32;
        float bb = bias[f];
        if (mat == 0) {
            #pragma unroll
            for (int r = 0; r < 16; ++r) {
                int p = (r & 3) + 8 * (r >> 2) + 4 * hi;
                Qlds[p * 168 + f] = f2bf(acc[r] + bb);
            }
        } else if (mat == 1) {
            #pragma unroll
            for (int r = 0; r < 16; ++r) {
                int p = (r & 3) + 8 * (r >> 2) + 4 * hi;
                Klds[p * 168 + f] = f2bf(acc[r] + bb);
            }
        } else {
            #pragma unroll
            for (int r = 0; r < 16; ++r) {
                int p = (r & 3) + 8 * (r >> 2) + 4 * hi;
                Vtl[f * 40 + p] = f2bf(acc[r] + bb);   // transposed: [e][q]
            }
        }
    }
    __syncthreads();

    // ---- S = Q K^T (redundant per wave); softmax over p ----
    floatx16 S = {0.f, 0.f, 0.f, 0.f, 0.f, 0.f, 0.f, 0.f,
                  0.f, 0.f, 0.f, 0.f, 0.f, 0.f, 0.f, 0.f};
    #pragma unroll
    for (int kc = 0; kc < 10; ++kc) {
        int e0 = kc * 16;
        short8 aq = *(const short8*)(Qlds + l32 * 168 + e0 + hi * 8);
        short8 bk2 = *(const short8*)(Klds + l32 * 168 + e0 + hi * 8);
        S = __builtin_amdgcn_mfma_f32_32x32x16_bf16(aq, bk2, S, 0, 0, 0);
    }
    float mx = -1e30f;
    #pragma unroll
    for (int r = 0; r < 16; ++r) { S[r] *= INV_SCALE; mx = fmaxf(mx, S[r]); }
    mx = fmaxf(mx, __shfl_xor(mx, 32));
    float ex[16];
    float sum = 0.f;
    #pragma unroll
    for (int r = 0; r < 16; ++r) { ex[r] = expf(S[r] - mx); sum += ex[r]; }
    sum += __shfl_xor(sum, 32);
    float inv = 1.f / sum;
    if (wid == 0) {
        #pragma unroll
        for (int r = 0; r < 16; ++r) {
            int p = (r & 3) + 8 * (r >> 2) + 4 * hi;
            Satt[p * 40 + l32] = f2bf(ex[r] * inv);
        }
    }
    __syncthreads();   // att ready; Q/K dead -> region1 becomes h

    // ---- PV + residual: h (LDS f32) and x2 (LDS bf16, over xn) ----
    short8 a0 = *(const short8*)(Satt + l32 * 40 + hi * 8);
    short8 a1 = *(const short8*)(Satt + l32 * 40 + 16 + hi * 8);
    const float* clr = cl + (size_t)b * D_TRF;
    float gg = bt_gain[0], bb2 = bt_bias[0];
    for (int t = wid; t < 5; t += 4) {
        int e0 = t * 32;
        short8 b0 = *(const short8*)(Vtl + (e0 + l32) * 40 + hi * 8);
        short8 b1 = *(const short8*)(Vtl + (e0 + l32) * 40 + 16 + hi * 8);
        floatx16 acc = {0.f, 0.f, 0.f, 0.f, 0.f, 0.f, 0.f, 0.f,
                        0.f, 0.f, 0.f, 0.f, 0.f, 0.f, 0.f, 0.f};
        acc = __builtin_amdgcn_mfma_f32_32x32x16_bf16(a0, b0, acc, 0, 0, 0);
        acc = __builtin_amdgcn_mfma_f32_32x32x16_bf16(a1, b1, acc, 0, 0, 0);
        #pragma unroll
        for (int r = 0; r < 16; ++r) {
            int p = (r & 3) + 8 * (r >> 2) + 4 * hi;
            int e = e0 + l32;
            float hv = acc[r] + clr[p * E_ + e];
            hlds[p * 168 + e] = hv;
            xnl[p * 168 + e] = f2bf(hv * gg + bb2);   // x2
        }
    }
    __syncthreads();   // h, x2 ready

    // ---- BT: o[p][f] = sum_e x2[p][e] wtb[f][e] + bt_b; supact; + h -> yb ----
    for (int tc = wid; tc < 5; tc += 4) {
        int f0 = tc * 32;
        floatx16 acc = {0.f, 0.f, 0.f, 0.f, 0.f, 0.f, 0.f, 0.f,
                        0.f, 0.f, 0.f, 0.f, 0.f, 0.f, 0.f, 0.f};
        #pragma unroll
        for (int kc = 0; kc < 10; ++kc) {
            int e0 = kc * 16;
            short8 af = *(const short8*)(xnl + l32 * 168 + e0 + hi * 8);
            short8 bf = *(const short8*)(wtb + (size_t)(f0 + l32) * E_ + e0 + hi * 8);
            acc = __builtin_amdgcn_mfma_f32_32x32x16_bf16(af, bf, acc, 0, 0, 0);
        }
        int f = f0 + l32;
        float bb = bt_b[f];
        #pragma unroll
        for (int r = 0; r < 16; ++r) {
            int p = (r & 3) + 8 * (r >> 2) + 4 * hi;
            int i = p * E_ + f;
            float o = acc[r] + bb;
            float sig = 1.f / (1.f + expf(-sup_b[i] * o));
            float y = (sup_g[i] + sig * (1.f - sup_g[i])) * o + hlds[p * 168 + f];
            yb[((size_t)b * 32 + p) * E_ + f] = f2bf(y);
        }
    }
}

// ---------------------------------------------------------------------------
// K7: head GEMM v10 (unchanged this round) — m97 template + counted vmcnt.
// ---------------------------------------------------------------------------
__global__ __launch_bounds__(256, 2) void k_lin10(const unsigned short* __restrict__ yb,
                                                  const unsigned short* __restrict__ wb,
                                                  float* __restrict__ pb) {
    __shared__ __align__(16) unsigned short As[2][128 * 64];  // 2 x 16 KB
    __shared__ __align__(16) unsigned short Bs[2][96 * 64];   // 2 x 12 KB

    int bid = blockIdx.x;
    int xcd = bid & 7, j = bid >> 3;
    int nt = xcd * 4 + (j & 3);          // 0..31  (96-col tiles)
    int mt = (j >> 2) & 3;               // 0..3   (128-row tiles)
    int sp = j >> 4;                     // 0..3   (split-K, 1280 each)

    int tid = threadIdx.x, wid = tid >> 6, lane = tid & 63;
    int l16 = lane & 15, quad = lane >> 4;
    int wr = wid >> 1, wc = wid & 1;     // 2x2 wave grid

    const size_t aRow0 = (size_t)(mt * 128) * D_TRF;
    const size_t bRow0 = (size_t)(nt * 96) * D_TRF;
    const int k0 = sp * 1280;

    floatx4 acc[4][3];
    #pragma unroll
    for (int fi = 0; fi < 4; ++fi)
        #pragma unroll
        for (int fj = 0; fj < 3; ++fj) acc[fi][fj] = (floatx4){0.f, 0.f, 0.f, 0.f};

    int aOff[4][2], bOff[3][2];
    #pragma unroll
    for (int fi = 0; fi < 4; ++fi) {
        int row = wr * 64 + fi * 16 + l16;
        #pragma unroll
        for (int kk = 0; kk < 2; ++kk)
            aOff[fi][kk] = row * 64 + (((quad + kk * 4) ^ (row & 7)) * 8);
    }
    #pragma unroll
    for (int fj = 0; fj < 3; ++fj) {
        int row = wc * 48 + fj * 16 + l16;
        #pragma unroll
        for (int kk = 0; kk < 2; ++kk)
            bOff[fj][kk] = row * 64 + (((quad + kk * 4) ^ (row & 7)) * 8);
    }

#define STAGE10(buf, t)                                                         \
    do {                                                                        \
        int kh_ = k0 + (t) * 64;                                                \
        _Pragma("unroll")                                                       \
        for (int i_ = 0; i_ < 4; ++i_) {                                        \
            int u_ = i_ * 256 + tid;                                            \
            int row_ = u_ >> 3, c_ = u_ & 7;                                    \
            load_lds16(yb + aRow0 + (size_t)row_ * D_TRF + kh_ +                \
                           ((c_ ^ (row_ & 7)) * 8),                             \
                       (char*)(&As[buf][0]) + (size_t)u_ * 16);                 \
        }                                                                       \
        _Pragma("unroll")                                                       \
        for (int i_ = 0; i_ < 3; ++i_) {                                        \
            int u_ = i_ * 256 + tid;                                            \
            int row_ = u_ >> 3, c_ = u_ & 7;                                    \
            load_lds16(wb + bRow0 + (size_t)row_ * D_TRF + kh_ +                \
                           ((c_ ^ (row_ & 7)) * 8),                             \
                       (char*)(&Bs[buf][0]) + (size_t)u_ * 16);                 \
        }                                                                       \
    } while (0)

    STAGE10(0, 0);                            // 7 in flight; no wait here

    for (int t = 0; t < 20; ++t) {
        int cur = t & 1;
        if (t < 19) {
            STAGE10(cur ^ 1, t + 1);          // -> 14 in flight
            asm volatile("s_waitcnt vmcnt(7)" ::: "memory");   // tile t landed
        } else {
            asm volatile("s_waitcnt vmcnt(0)" ::: "memory");   // last tile
        }
        __builtin_amdgcn_s_barrier();         // raw: does NOT drain vmcnt

        const unsigned short* Ab = &As[cur][0];
        const unsigned short* Bb = &Bs[cur][0];
        short8 af[4][2], bfr[3][2];
        #pragma unroll
        for (int fi = 0; fi < 4; ++fi)
            #pragma unroll
            for (int kk = 0; kk < 2; ++kk)
                af[fi][kk] = *(const short8*)(Ab + aOff[fi][kk]);
        #pragma unroll
        for (int fj = 0; fj < 3; ++fj)
            #pragma unroll
            for (int kk = 0; kk < 2; ++kk)
                bfr[fj][kk] = *(const short8*)(Bb + bOff[fj][kk]);

        #pragma unroll
        for (int kk = 0; kk < 2; ++kk)
            #pragma unroll
            for (int fi = 0; fi < 4; ++fi)
                #pragma unroll
                for (int fj = 0; fj < 3; ++fj)
                    acc[fi][fj] = __builtin_amdgcn_mfma_f32_16x16x32_bf16(
                        af[fi][kk], bfr[fj][kk], acc[fi][fj], 0, 0, 0);

        asm volatile("s_waitcnt lgkmcnt(0)" ::: "memory");  // all ds_reads done
        __builtin_amdgcn_s_barrier();         // guards buf overwrite next iter
    }
#undef STAGE10

    #pragma unroll
    for (int fi = 0; fi < 4; ++fi) {
        int row = mt * 128 + wr * 64 + fi * 16 + quad * 4;
        #pragma unroll
        for (int fj = 0; fj < 3; ++fj) {
            int col = nt * 96 + wc * 48 + fj * 16 + l16;
            #pragma unroll
            for (int r = 0; r < 4; ++r)
                pb[((size_t)(sp * 512 + row + r)) * 3072 + col] = acc[fi][fj][r];
        }
    }
}

// ---------------------------------------------------------------------------
// K8: reduce 4 split-K partials + bias/gain -> out [512,3000]
// ---------------------------------------------------------------------------
__global__ __launch_bounds__(256) void k_red(const float* __restrict__ pb,
                                             const float* __restrict__ lin_b,
                                             const float* __restrict__ out_gain,
                                             const float* __restrict__ out_bias,
                                             float* __restrict__ out) {
    int col = blockIdx.x * 256 + threadIdx.x;
    if (col >= D_OUT) return;
    int row = blockIdx.y;
    size_t base = (size_t)row * 3072 + col;
    const size_t stride = (size_t)512 * 3072;
    float s = pb[base] + pb[base + stride] + pb[base + 2 * stride] + pb[base + 3 * stride];
    float g = out_gain[0];
    out[(size_t)row * D_OUT + col] = s * g + lin_b[col] * g + out_bias[0];
}

// ---------------------------------------------------------------------------
// Workspace layout (bytes)
// ---------------------------------------------------------------------------
#define SZ_ROWF ((size_t)B_ * D_TRF * 4)           // 10,485,760
#define SZ_ROWB ((size_t)B_ * D_TRF * 2)           // 5,242,880
#define OFF_CL  ((size_t)0)
#define OFF_H   (OFF_CL + SZ_ROWF)                 // (unused after fusion)
#define OFF_XN  (OFF_H + SZ_ROWF)                  // xn bf16
#define OFF_QB  (OFF_XN + SZ_ROWB)                 // (unused after fusion)
#define OFF_KB  (OFF_QB + SZ_ROWB)                 // (unused after fusion)
#define OFF_VB  (OFF_KB + SZ_ROWB)                 // (unused after fusion)
#define OFF_YB  (OFF_VB + SZ_ROWB)
#define OFF_WSM (OFF_YB + SZ_ROWB)                 // 4 x 51200 B
#define OFF_WB  (OFF_WSM + (size_t)4 * E_ * E_ * 2)
// pb (4*512*3072*4 = 25,165,824 B) aliases OFF_CL..: cl and xn are dead
// once k_qab has run, and 25.2 MB < OFF_YB (26.2 MB) -> yb untouched.

extern "C" void kernel_launch(void* const* d_in, const int* in_sizes, int n_in,
                              void* d_out, int out_size, void* d_ws, size_t ws_size,
                              hipStream_t stream) {
    const float* x        = (const float*)d_in[0];
    const float* stdv     = (const float*)d_in[1];
    const float* meanv    = (const float*)d_in[2];
    const float* mat      = (const float*)d_in[3];
    const float* ln_g     = (const float*)d_in[4];
    const float* ln_b     = (const float*)d_in[5];
    const float* wq       = (const float*)d_in[6];
    const float* bq       = (const float*)d_in[7];
    const float* wk       = (const float*)d_in[8];
    const float* bk       = (const float*)d_in[9];
    const float* wv       = (const float*)d_in[10];
    const float* bv       = (const float*)d_in[11];
    const float* bt_w     = (const float*)d_in[12];
    const float* bt_b     = (const float*)d_in[13];
    const float* bt_gain  = (const float*)d_in[14];
    const float* bt_bias  = (const float*)d_in[15];
    const float* sup_g    = (const float*)d_in[16];
    const float* sup_b    = (const float*)d_in[17];
    const float* lin_w    = (const float*)d_in[18];
    const float* lin_b    = (const float*)d_in[19];
    const float* out_gain = (const float*)d_in[20];
    const float* out_bias = (const float*)d_in[21];

    char* ws = (char*)d_ws;
    float* cl = (float*)(ws + OFF_CL);
    unsigned short* xn  = (unsigned short*)(ws + OFF_XN);
    unsigned short* yb  = (unsigned short*)(ws + OFF_YB);
    unsigned short* wqb = (unsigned short*)(ws + OFF_WSM);
    unsigned short* wkb = wqb + E_ * E_;
    unsigned short* wvb = wkb + E_ * E_;
    unsigned short* wtb = wvb + E_ * E_;
    unsigned short* wb  = (unsigned short*)(ws + OFF_WB);
    float* pb = (float*)(ws + OFF_CL);   // aliases cl/xn (dead by k_lin10)
    float* out = (float*)d_out;

    k_castw<<<15360, 256, 0, stream>>>(lin_w, wb);
    k_cast_small<<<100, 256, 0, stream>>>(wq, wk, wv, bt_w, wqb, wkb, wvb, wtb);
    k_cl<<<dim3(64, 4), 256, 0, stream>>>(x, stdv, meanv, mat, cl);
    k_ln<<<512, 256, 0, stream>>>(cl, ln_g, ln_b, xn);
    k_qab<<<512, 256, 0, stream>>>(xn, cl, wqb, wkb, wvb, wtb, bq, bk, bv,
                                   bt_b, bt_gain, bt_bias, sup_g, sup_b, yb);
    k_lin10<<<512, 256, 0, stream>>>(yb, wb, pb);
    k_red<<<dim3(12, 512), 256, 0, stream>>>(pb, lin_b, out_gain, out_bias, out);
}

// Round 6
// 225.216 us; speedup vs baseline: 1.2776x; 1.0903x over previous
//
#include <hip/hip_runtime.h>

// Problem constants
#define B_    512
#define D_TRF 5120
#define P_    32
#define E_    160
#define D_OUT 3000
#define PAD_  61
#define D_CL  4998
#define INV_SCALE 0.07905694150420949f   // 1/sqrt(160)
#define N_PAD 3072          // lin_w rows padded (32 tiles of 96)

typedef __attribute__((ext_vector_type(4))) float floatx4;
typedef __attribute__((ext_vector_type(16))) float floatx16;
typedef __attribute__((ext_vector_type(8))) short short8;

static __device__ __forceinline__ unsigned short f2bf(float f) {
    unsigned int u = __float_as_uint(f);
    unsigned int r = (u + 0x7fffu + ((u >> 16) & 1u)) >> 16;
    return (unsigned short)r;
}
static __device__ __forceinline__ float bf2f(unsigned short u) {
    return __uint_as_float(((unsigned int)u) << 16);
}
static __device__ __forceinline__ void load_lds16(const void* g, void* lds) {
    __builtin_amdgcn_global_load_lds(
        (const __attribute__((address_space(1))) unsigned int*)g,
        (__attribute__((address_space(3))) unsigned int*)lds, 16, 0, 0);
}

// ---------------------------------------------------------------------------
// K0: cast lin_w [3000,5120] f32 -> [3072,5120] bf16 (pad rows zeroed)
// ---------------------------------------------------------------------------
__global__ __launch_bounds__(256) void k_castw(const float* __restrict__ w,
                                               unsigned short* __restrict__ wb) {
    size_t i4 = ((size_t)blockIdx.x * 256 + threadIdx.x) * 4;
    size_t o = i4 / D_TRF;
    ushort4 s;
    if (o < D_OUT) {
        float4 v = *(const float4*)(w + i4);
        s.x = f2bf(v.x); s.y = f2bf(v.y); s.z = f2bf(v.z); s.w = f2bf(v.w);
    } else {
        s.x = s.y = s.z = s.w = 0;
    }
    *(ushort4*)(wb + i4) = s;
}

// ---------------------------------------------------------------------------
// K0b: cast wq/wk/wv ([f][e], already B-operand layout) to bf16;
//      transpose bt_w -> wtb[f][e] = bt_w[e][f].
// ---------------------------------------------------------------------------
__global__ __launch_bounds__(256) void k_cast_small(const float* __restrict__ wq,
                                                    const float* __restrict__ wk,
                                                    const float* __restrict__ wv,
                                                    const float* __restrict__ btw,
                                                    unsigned short* __restrict__ wqb,
                                                    unsigned short* __restrict__ wkb,
                                                    unsigned short* __restrict__ wvb,
                                                    unsigned short* __restrict__ wtb) {
    int idx = blockIdx.x * 256 + threadIdx.x;   // < 25600
    wqb[idx] = f2bf(wq[idx]);
    wkb[idx] = f2bf(wk[idx]);
    wvb[idx] = f2bf(wv[idx]);
    int f = idx / E_, e = idx - f * E_;
    wtb[idx] = f2bf(btw[(size_t)e * E_ + f]);
}

// ---------------------------------------------------------------------------
// K1: cl = (x*std+mean) @ mat, with 61-zero pad both sides -> [512,5120]
// ---------------------------------------------------------------------------
__global__ __launch_bounds__(256) void k_cl(const float* __restrict__ x,
                                            const float* __restrict__ stdv,
                                            const float* __restrict__ meanv,
                                            const float* __restrict__ mat,
                                            float* __restrict__ cl) {
    int bg = blockIdx.x, jc = blockIdx.y, tid = threadIdx.x;
    __shared__ float t[8 * 64];
    for (int idx = tid; idx < 8 * 64; idx += 256) {
        int i = idx >> 6, k = idx & 63;
        t[idx] = x[(size_t)(bg * 8 + i) * 64 + k] * stdv[k] + meanv[k];
    }
    __syncthreads();

    if (jc == 0) {
        for (int idx = tid; idx < 8 * PAD_; idx += 256) {
            int i = idx / PAD_, jj = idx - i * PAD_;
            cl[(size_t)(bg * 8 + i) * D_TRF + jj] = 0.f;
        }
    } else if (jc == 3) {
        for (int idx = tid; idx < 8 * PAD_; idx += 256) {
            int i = idx / PAD_, jj = idx - i * PAD_;
            cl[(size_t)(bg * 8 + i) * D_TRF + (D_TRF - PAD_) + jj] = 0.f;
        }
    }

    int j0 = jc * 1250;
    int jend = min(D_CL, j0 + 1250);
    for (int j = j0 + tid; j < jend; j += 256) {
        float acc[8] = {};
        #pragma unroll 16
        for (int k = 0; k < 64; ++k) {
            float m = mat[(size_t)k * D_CL + j];
            #pragma unroll
            for (int i = 0; i < 8; ++i) acc[i] += t[i * 64 + k] * m;
        }
        #pragma unroll
        for (int i = 0; i < 8; ++i)
            cl[(size_t)(bg * 8 + i) * D_TRF + PAD_ + j] = acc[i];
    }
}

// ---------------------------------------------------------------------------
// K2: LayerNorm cl row -> xn bf16 [16384,160]. grid = 512 (one b each)
// ---------------------------------------------------------------------------
__global__ __launch_bounds__(256) void k_ln(const float* __restrict__ cl,
                                            const float* __restrict__ ln_g,
                                            const float* __restrict__ ln_b,
                                            unsigned short* __restrict__ xn) {
    int b = blockIdx.x, tid = threadIdx.x;
    __shared__ float redA[4], redB[4];
    __shared__ float sMu, sRstd;
    const float* row = cl + (size_t)b * D_TRF;

    float s = 0.f, s2 = 0.f;
    #pragma unroll
    for (int it = 0; it < 5; ++it) {
        int i4 = (it * 256 + tid) * 4;
        float4 v = *(const float4*)(row + i4);
        s += v.x + v.y + v.z + v.w;
        s2 += v.x * v.x + v.y * v.y + v.z * v.z + v.w * v.w;
    }
    #pragma unroll
    for (int off = 32; off; off >>= 1) {
        s  += __shfl_down(s, off);
        s2 += __shfl_down(s2, off);
    }
    if ((tid & 63) == 0) { redA[tid >> 6] = s; redB[tid >> 6] = s2; }
    __syncthreads();
    if (tid == 0) {
        float S = redA[0] + redA[1] + redA[2] + redA[3];
        float S2 = redB[0] + redB[1] + redB[2] + redB[3];
        float mu = S / (float)D_TRF;
        float var = S2 / (float)D_TRF - mu * mu;
        sMu = mu; sRstd = rsqrtf(var + 1e-5f);
    }
    __syncthreads();
    float mu = sMu, rs = sRstd;
    #pragma unroll
    for (int it = 0; it < 5; ++it) {
        int i4 = (it * 256 + tid) * 4;
        float4 v = *(const float4*)(row + i4);
        float4 g = *(const float4*)(ln_g + i4);
        float4 be = *(const float4*)(ln_b + i4);
        ushort4 o;
        o.x = f2bf((v.x - mu) * rs * g.x + be.x);
        o.y = f2bf((v.y - mu) * rs * g.y + be.y);
        o.z = f2bf((v.z - mu) * rs * g.z + be.z);
        o.w = f2bf((v.w - mu) * rs * g.w + be.w);
        *(ushort4*)(xn + (size_t)b * D_TRF + i4) = o;
    }
}

// ---------------------------------------------------------------------------
// K3456 v2: fused QKV + attention + Better_Transformer, one block per b,
// 8 waves (512 thr). v1 (42 us) was latency-bound: MfmaUtil 3.4%, VALUBusy
// 13%, Occ 14.6% — all idle; per-wave 4 serial QKV tiles + redundant QK^T
// x4 + cold-cl PV stall dominated. v2: (a) 8 waves halve serial tiles/wave
// and double waves/CU to 16; (b) cl staged to LDS via global_load_lds at
// kernel start (T14: drains with first barrier, PV reads LDS; region then
// reused in-place as h); (c) QK^T+softmax wave-0-only; (d) __expf.
// LDS 68096 B -> 2 blocks/CU.
//   clh  f32 [32][160] 20480 (cl -> h in-place)
//   Qlds/Klds bf16 [32][168] 2x10752 (dead after QK^T)
//   Vtl bf16 [160][40] 12800    Satt bf16 [32][40] 2560
//   xnl bf16 [32][168] 10752 (xn -> x2 in-place)
// ---------------------------------------------------------------------------
__global__ __launch_bounds__(512) void k_qab(const unsigned short* __restrict__ xn,
                                             const float* __restrict__ cl,
                                             const unsigned short* __restrict__ wqb,
                                             const unsigned short* __restrict__ wkb,
                                             const unsigned short* __restrict__ wvb,
                                             const unsigned short* __restrict__ wtb,
                                             const float* __restrict__ bq,
                                             const float* __restrict__ bk,
                                             const float* __restrict__ bv,
                                             const float* __restrict__ bt_b,
                                             const float* __restrict__ bt_gain,
                                             const float* __restrict__ bt_bias,
                                             const float* __restrict__ sup_g,
                                             const float* __restrict__ sup_b,
                                             unsigned short* __restrict__ yb) {
    __shared__ __align__(16) char smem[68096];
    float*          clh  = (float*)smem;                              // [32][160] cl -> h
    unsigned short* Qlds = (unsigned short*)(smem + 20480);           // [32][168]
    unsigned short* Klds = Qlds + 32 * 168;                           // [32][168]
    unsigned short* Vtl  = (unsigned short*)(smem + 41984);           // [160][40]
    unsigned short* Satt = (unsigned short*)(smem + 54784);           // [32][40]
    unsigned short* xnl  = (unsigned short*)(smem + 57344);           // [32][168] -> x2

    int b = blockIdx.x;
    int tid = threadIdx.x, wid = tid >> 6, lane = tid & 63;
    int l32 = lane & 31, hi = lane >> 5;

    // ---- T14: stage cl[b] (5120 f32 contiguous = 1280 x 16B) via
    //      global_load_lds; linear dest = wave-uniform base + lane*16. ----
    const float* clg = cl + (size_t)b * D_TRF;
    #pragma unroll
    for (int it = 0; it < 3; ++it) {
        int u = it * 512 + tid;
        if (u < 1280)
            load_lds16(clg + u * 4, (char*)clh + (size_t)u * 16);
    }

    // ---- stage xn[b] (32x160 bf16) -> LDS padded rows (reg round-trip:
    //      padded dest breaks the gload_lds lane-linearity rule) ----
    const unsigned short* xg = xn + (size_t)b * D_TRF;
    {
        int u = tid;
        if (u < 640) {   // wait: 640 of 512 -> two strides
            int row = u / 20, c = u - row * 20;
            *(short8*)(xnl + row * 168 + c * 8) = *(const short8*)(xg + row * 160 + c * 8);
        }
        u = 512 + tid;
        if (u < 640) {
            int row = u / 20, c = u - row * 20;
            *(short8*)(xnl + row * 168 + c * 8) = *(const short8*)(xg + row * 160 + c * 8);
        }
    }
    __syncthreads();   // xn + cl staged (syncthreads drains vmcnt)

    // ---- QKV: 15 32x32 tiles (3 mats x 5 col-tiles), 8 waves strided ----
    for (int tc = wid; tc < 15; tc += 8) {
        int mat = tc / 5, f0 = (tc - mat * 5) * 32;
        const unsigned short* wsrc = (mat == 0) ? wqb : (mat == 1) ? wkb : wvb;
        const float* bias          = (mat == 0) ? bq  : (mat == 1) ? bk  : bv;
        floatx16 acc = {0.f, 0.f, 0.f, 0.f, 0.f, 0.f, 0.f, 0.f,
                        0.f, 0.f, 0.f, 0.f, 0.f, 0.f, 0.f, 0.f};
        #pragma unroll
        for (int kc = 0; kc < 10; ++kc) {
            int e0 = kc * 16;
            short8 af = *(const short8*)(xnl + l32 * 168 + e0 + hi * 8);
            short8 bf = *(const short8*)(wsrc + (size_t)(f0 + l32) * E_ + e0 + hi * 8);
            acc = __builtin_amdgcn_mfma_f32_32x32x16_bf16(af, bf, acc, 0, 0, 0);
        }
        int f = f0 + l32;
        float bb = bias[f];
        if (mat == 0) {
            #pragma unroll
            for (int r = 0; r < 16; ++r) {
                int p = (r & 3) + 8 * (r >> 2) + 4 * hi;
                Qlds[p * 168 + f] = f2bf(acc[r] + bb);
            }
        } else if (mat == 1) {
            #pragma unroll
            for (int r = 0; r < 16; ++r) {
                int p = (r & 3) + 8 * (r >> 2) + 4 * hi;
                Klds[p * 168 + f] = f2bf(acc[r] + bb);
            }
        } else {
            #pragma unroll
            for (int r = 0; r < 16; ++r) {
                int p = (r & 3) + 8 * (r >> 2) + 4 * hi;
                Vtl[f * 40 + p] = f2bf(acc[r] + bb);   // transposed: [e][q]
            }
        }
    }
    __syncthreads();

    // ---- S = Q K^T + softmax over p: wave 0 only (others' S was unused) ----
    if (wid == 0) {
        floatx16 S = {0.f, 0.f, 0.f, 0.f, 0.f, 0.f, 0.f, 0.f,
                      0.f, 0.f, 0.f, 0.f, 0.f, 0.f, 0.f, 0.f};
        #pragma unroll
        for (int kc = 0; kc < 10; ++kc) {
            int e0 = kc * 16;
            short8 aq = *(const short8*)(Qlds + l32 * 168 + e0 + hi * 8);
            short8 bk2 = *(const short8*)(Klds + l32 * 168 + e0 + hi * 8);
            S = __builtin_amdgcn_mfma_f32_32x32x16_bf16(aq, bk2, S, 0, 0, 0);
        }
        float mx = -1e30f;
        #pragma unroll
        for (int r = 0; r < 16; ++r) { S[r] *= INV_SCALE; mx = fmaxf(mx, S[r]); }
        mx = fmaxf(mx, __shfl_xor(mx, 32));
        float ex[16];
        float sum = 0.f;
        #pragma unroll
        for (int r = 0; r < 16; ++r) { ex[r] = __expf(S[r] - mx); sum += ex[r]; }
        sum += __shfl_xor(sum, 32);
        float inv = 1.f / sum;
        #pragma unroll
        for (int r = 0; r < 16; ++r) {
            int p = (r & 3) + 8 * (r >> 2) + 4 * hi;
            Satt[p * 40 + l32] = f2bf(ex[r] * inv);
        }
    }
    __syncthreads();   // att ready; Q/K dead

    // ---- PV + residual: h = att.V + cl, in LDS (clh in-place) ----
    short8 a0 = *(const short8*)(Satt + l32 * 40 + hi * 8);
    short8 a1 = *(const short8*)(Satt + l32 * 40 + 16 + hi * 8);
    float gg = bt_gain[0], bb2 = bt_bias[0];
    if (wid < 5) {
        int e0 = wid * 32;
        short8 b0 = *(const short8*)(Vtl + (e0 + l32) * 40 + hi * 8);
        short8 b1 = *(const short8*)(Vtl + (e0 + l32) * 40 + 16 + hi * 8);
        floatx16 acc = {0.f, 0.f, 0.f, 0.f, 0.f, 0.f, 0.f, 0.f,
                        0.f, 0.f, 0.f, 0.f, 0.f, 0.f, 0.f, 0.f};
        acc = __builtin_amdgcn_mfma_f32_32x32x16_bf16(a0, b0, acc, 0, 0, 0);
        acc = __builtin_amdgcn_mfma_f32_32x32x16_bf16(a1, b1, acc, 0, 0, 0);
        #pragma unroll
        for (int r = 0; r < 16; ++r) {
            int p = (r & 3) + 8 * (r >> 2) + 4 * hi;
            int e = e0 + l32;
            float hv = acc[r] + clh[p * E_ + e];   // read cl, then overwrite as h
            clh[p * E_ + e] = hv;
            xnl[p * 168 + e] = f2bf(hv * gg + bb2);   // x2
        }
    }
    __syncthreads();   // h, x2 ready

    // ---- BT: o[p][f] = sum_e x2[p][e] wtb[f][e] + bt_b; supact; + h -> yb ----
    if (wid < 5) {
        int f0 = wid * 32;
        floatx16 acc = {0.f, 0.f, 0.f, 0.f, 0.f, 0.f, 0.f, 0.f,
                        0.f, 0.f, 0.f, 0.f, 0.f, 0.f, 0.f, 0.f};
        #pragma unroll
        for (int kc = 0; kc < 10; ++kc) {
            int e0 = kc * 16;
            short8 af = *(const short8*)(xnl + l32 * 168 + e0 + hi * 8);
            short8 bf = *(const short8*)(wtb + (size_t)(f0 + l32) * E_ + e0 + hi * 8);
            acc = __builtin_amdgcn_mfma_f32_32x32x16_bf16(af, bf, acc, 0, 0, 0);
        }
        int f = f0 + l32;
        float bb = bt_b[f];
        #pragma unroll
        for (int r = 0; r < 16; ++r) {
            int p = (r & 3) + 8 * (r >> 2) + 4 * hi;
            int i = p * E_ + f;
            float o = acc[r] + bb;
            float sig = 1.f / (1.f + __expf(-sup_b[i] * o));
            float y = (sup_g[i] + sig * (1.f - sup_g[i])) * o + clh[p * E_ + f];
            yb[((size_t)b * 32 + p) * E_ + f] = f2bf(y);
        }
    }
}

// ---------------------------------------------------------------------------
// K7: head GEMM v10 (unchanged) — m97 template + counted vmcnt.
// ---------------------------------------------------------------------------
__global__ __launch_bounds__(256, 2) void k_lin10(const unsigned short* __restrict__ yb,
                                                  const unsigned short* __restrict__ wb,
                                                  float* __restrict__ pb) {
    __shared__ __align__(16) unsigned short As[2][128 * 64];  // 2 x 16 KB
    __shared__ __align__(16) unsigned short Bs[2][96 * 64];   // 2 x 12 KB

    int bid = blockIdx.x;
    int xcd = bid & 7, j = bid >> 3;
    int nt = xcd * 4 + (j & 3);          // 0..31  (96-col tiles)
    int mt = (j >> 2) & 3;               // 0..3   (128-row tiles)
    int sp = j >> 4;                     // 0..3   (split-K, 1280 each)

    int tid = threadIdx.x, wid = tid >> 6, lane = tid & 63;
    int l16 = lane & 15, quad = lane >> 4;
    int wr = wid >> 1, wc = wid & 1;     // 2x2 wave grid

    const size_t aRow0 = (size_t)(mt * 128) * D_TRF;
    const size_t bRow0 = (size_t)(nt * 96) * D_TRF;
    const int k0 = sp * 1280;

    floatx4 acc[4][3];
    #pragma unroll
    for (int fi = 0; fi < 4; ++fi)
        #pragma unroll
        for (int fj = 0; fj < 3; ++fj) acc[fi][fj] = (floatx4){0.f, 0.f, 0.f, 0.f};

    int aOff[4][2], bOff[3][2];
    #pragma unroll
    for (int fi = 0; fi < 4; ++fi) {
        int row = wr * 64 + fi * 16 + l16;
        #pragma unroll
        for (int kk = 0; kk < 2; ++kk)
            aOff[fi][kk] = row * 64 + (((quad + kk * 4) ^ (row & 7)) * 8);
    }
    #pragma unroll
    for (int fj = 0; fj < 3; ++fj) {
        int row = wc * 48 + fj * 16 + l16;
        #pragma unroll
        for (int kk = 0; kk < 2; ++kk)
            bOff[fj][kk] = row * 64 + (((quad + kk * 4) ^ (row & 7)) * 8);
    }

#define STAGE10(buf, t)                                                         \
    do {                                                                        \
        int kh_ = k0 + (t) * 64;                                                \
        _Pragma("unroll")                                                       \
        for (int i_ = 0; i_ < 4; ++i_) {                                        \
            int u_ = i_ * 256 + tid;                                            \
            int row_ = u_ >> 3, c_ = u_ & 7;                                    \
            load_lds16(yb + aRow0 + (size_t)row_ * D_TRF + kh_ +                \
                           ((c_ ^ (row_ & 7)) * 8),                             \
                       (char*)(&As[buf][0]) + (size_t)u_ * 16);                 \
        }                                                                       \
        _Pragma("unroll")                                                       \
        for (int i_ = 0; i_ < 3; ++i_) {                                        \
            int u_ = i_ * 256 + tid;                                            \
            int row_ = u_ >> 3, c_ = u_ & 7;                                    \
            load_lds16(wb + bRow0 + (size_t)row_ * D_TRF + kh_ +                \
                           ((c_ ^ (row_ & 7)) * 8),                             \
                       (char*)(&Bs[buf][0]) + (size_t)u_ * 16);                 \
        }                                                                       \
    } while (0)

    STAGE10(0, 0);                            // 7 in flight; no wait here

    for (int t = 0; t < 20; ++t) {
        int cur = t & 1;
        if (t < 19) {
            STAGE10(cur ^ 1, t + 1);          // -> 14 in flight
            asm volatile("s_waitcnt vmcnt(7)" ::: "memory");   // tile t landed
        } else {
            asm volatile("s_waitcnt vmcnt(0)" ::: "memory");   // last tile
        }
        __builtin_amdgcn_s_barrier();         // raw: does NOT drain vmcnt

        const unsigned short* Ab = &As[cur][0];
        const unsigned short* Bb = &Bs[cur][0];
        short8 af[4][2], bfr[3][2];
        #pragma unroll
        for (int fi = 0; fi < 4; ++fi)
            #pragma unroll
            for (int kk = 0; kk < 2; ++kk)
                af[fi][kk] = *(const short8*)(Ab + aOff[fi][kk]);
        #pragma unroll
        for (int fj = 0; fj < 3; ++fj)
            #pragma unroll
            for (int kk = 0; kk < 2; ++kk)
                bfr[fj][kk] = *(const short8*)(Bb + bOff[fj][kk]);

        #pragma unroll
        for (int kk = 0; kk < 2; ++kk)
            #pragma unroll
            for (int fi = 0; fi < 4; ++fi)
                #pragma unroll
                for (int fj = 0; fj < 3; ++fj)
                    acc[fi][fj] = __builtin_amdgcn_mfma_f32_16x16x32_bf16(
                        af[fi][kk], bfr[fj][kk], acc[fi][fj], 0, 0, 0);

        asm volatile("s_waitcnt lgkmcnt(0)" ::: "memory");  // all ds_reads done
        __builtin_amdgcn_s_barrier();         // guards buf overwrite next iter
    }
#undef STAGE10

    #pragma unroll
    for (int fi = 0; fi < 4; ++fi) {
        int row = mt * 128 + wr * 64 + fi * 16 + quad * 4;
        #pragma unroll
        for (int fj = 0; fj < 3; ++fj) {
            int col = nt * 96 + wc * 48 + fj * 16 + l16;
            #pragma unroll
            for (int r = 0; r < 4; ++r)
                pb[((size_t)(sp * 512 + row + r)) * 3072 + col] = acc[fi][fj][r];
        }
    }
}

// ---------------------------------------------------------------------------
// K8: reduce 4 split-K partials + bias/gain -> out [512,3000]
// ---------------------------------------------------------------------------
__global__ __launch_bounds__(256) void k_red(const float* __restrict__ pb,
                                             const float* __restrict__ lin_b,
                                             const float* __restrict__ out_gain,
                                             const float* __restrict__ out_bias,
                                             float* __restrict__ out) {
    int col = blockIdx.x * 256 + threadIdx.x;
    if (col >= D_OUT) return;
    int row = blockIdx.y;
    size_t base = (size_t)row * 3072 + col;
    const size_t stride = (size_t)512 * 3072;
    float s = pb[base] + pb[base + stride] + pb[base + 2 * stride] + pb[base + 3 * stride];
    float g = out_gain[0];
    out[(size_t)row * D_OUT + col] = s * g + lin_b[col] * g + out_bias[0];
}

// ---------------------------------------------------------------------------
// Workspace layout (bytes)
// ---------------------------------------------------------------------------
#define SZ_ROWF ((size_t)B_ * D_TRF * 4)           // 10,485,760
#define SZ_ROWB ((size_t)B_ * D_TRF * 2)           // 5,242,880
#define OFF_CL  ((size_t)0)
#define OFF_H   (OFF_CL + SZ_ROWF)                 // (unused after fusion)
#define OFF_XN  (OFF_H + SZ_ROWF)                  // xn bf16
#define OFF_QB  (OFF_XN + SZ_ROWB)                 // (unused after fusion)
#define OFF_KB  (OFF_QB + SZ_ROWB)                 // (unused after fusion)
#define OFF_VB  (OFF_KB + SZ_ROWB)                 // (unused after fusion)
#define OFF_YB  (OFF_VB + SZ_ROWB)
#define OFF_WSM (OFF_YB + SZ_ROWB)                 // 4 x 51200 B
#define OFF_WB  (OFF_WSM + (size_t)4 * E_ * E_ * 2)
// pb (4*512*3072*4 = 25,165,824 B) aliases OFF_CL..: cl and xn are dead
// once k_qab has run, and 25.2 MB < OFF_YB (26.2 MB) -> yb untouched.

extern "C" void kernel_launch(void* const* d_in, const int* in_sizes, int n_in,
                              void* d_out, int out_size, void* d_ws, size_t ws_size,
                              hipStream_t stream) {
    const float* x        = (const float*)d_in[0];
    const float* stdv     = (const float*)d_in[1];
    const float* meanv    = (const float*)d_in[2];
    const float* mat      = (const float*)d_in[3];
    const float* ln_g     = (const float*)d_in[4];
    const float* ln_b     = (const float*)d_in[5];
    const float* wq       = (const float*)d_in[6];
    const float* bq       = (const float*)d_in[7];
    const float* wk       = (const float*)d_in[8];
    const float* bk       = (const float*)d_in[9];
    const float* wv       = (const float*)d_in[10];
    const float* bv       = (const float*)d_in[11];
    const float* bt_w     = (const float*)d_in[12];
    const float* bt_b     = (const float*)d_in[13];
    const float* bt_gain  = (const float*)d_in[14];
    const float* bt_bias  = (const float*)d_in[15];
    const float* sup_g    = (const float*)d_in[16];
    const float* sup_b    = (const float*)d_in[17];
    const float* lin_w    = (const float*)d_in[18];
    const float* lin_b    = (const float*)d_in[19];
    const float* out_gain = (const float*)d_in[20];
    const float* out_bias = (const float*)d_in[21];

    char* ws = (char*)d_ws;
    float* cl = (float*)(ws + OFF_CL);
    unsigned short* xn  = (unsigned short*)(ws + OFF_XN);
    unsigned short* yb  = (unsigned short*)(ws + OFF_YB);
    unsigned short* wqb = (unsigned short*)(ws + OFF_WSM);
    unsigned short* wkb = wqb + E_ * E_;
    unsigned short* wvb = wkb + E_ * E_;
    unsigned short* wtb = wvb + E_ * E_;
    unsigned short* wb  = (unsigned short*)(ws + OFF_WB);
    float* pb = (float*)(ws + OFF_CL);   // aliases cl/xn (dead by k_lin10)
    float* out = (float*)d_out;

    k_castw<<<15360, 256, 0, stream>>>(lin_w, wb);
    k_cast_small<<<100, 256, 0, stream>>>(wq, wk, wv, bt_w, wqb, wkb, wvb, wtb);
    k_cl<<<dim3(64, 4), 256, 0, stream>>>(x, stdv, meanv, mat, cl);
    k_ln<<<512, 256, 0, stream>>>(cl, ln_g, ln_b, xn);
    k_qab<<<512, 512, 0, stream>>>(xn, cl, wqb, wkb, wvb, wtb, bq, bk, bv,
                                   bt_b, bt_gain, bt_bias, sup_g, sup_b, yb);
    k_lin10<<<512, 256, 0, stream>>>(yb, wb, pb);
    k_red<<<dim3(12, 512), 256, 0, stream>>>(pb, lin_b, out_gain, out_bias, out);
}

// Round 7
// 220.910 us; speedup vs baseline: 1.3025x; 1.0195x over previous
//
#include <hip/hip_runtime.h>

// Problem constants
#define B_    512
#define D_TRF 5120
#define P_    32
#define E_    160
#define D_OUT 3000
#define PAD_  61
#define D_CL  4998
#define INV_SCALE 0.07905694150420949f   // 1/sqrt(160)
#define N_PAD 3072          // lin_w rows padded (32 tiles of 96)

typedef __attribute__((ext_vector_type(4))) float floatx4;
typedef __attribute__((ext_vector_type(16))) float floatx16;
typedef __attribute__((ext_vector_type(8))) short short8;

static __device__ __forceinline__ unsigned short f2bf(float f) {
    unsigned int u = __float_as_uint(f);
    unsigned int r = (u + 0x7fffu + ((u >> 16) & 1u)) >> 16;
    return (unsigned short)r;
}
static __device__ __forceinline__ short8 pack8(float4 a, float4 b) {
    short8 o;
    o[0] = f2bf(a.x); o[1] = f2bf(a.y); o[2] = f2bf(a.z); o[3] = f2bf(a.w);
    o[4] = f2bf(b.x); o[5] = f2bf(b.y); o[6] = f2bf(b.z); o[7] = f2bf(b.w);
    return o;
}
static __device__ __forceinline__ void load_lds16(const void* g, void* lds) {
    __builtin_amdgcn_global_load_lds(
        (const __attribute__((address_space(1))) unsigned int*)g,
        (__attribute__((address_space(3))) unsigned int*)lds, 16, 0, 0);
}

// ---------------------------------------------------------------------------
// K0b: cast wq/wk/wv ([f][e], already B-operand layout) to bf16;
//      transpose bt_w -> wtb[f][e] = bt_w[e][f].
// ---------------------------------------------------------------------------
__global__ __launch_bounds__(256) void k_cast_small(const float* __restrict__ wq,
                                                    const float* __restrict__ wk,
                                                    const float* __restrict__ wv,
                                                    const float* __restrict__ btw,
                                                    unsigned short* __restrict__ wqb,
                                                    unsigned short* __restrict__ wkb,
                                                    unsigned short* __restrict__ wvb,
                                                    unsigned short* __restrict__ wtb) {
    int idx = blockIdx.x * 256 + threadIdx.x;   // < 25600
    wqb[idx] = f2bf(wq[idx]);
    wkb[idx] = f2bf(wk[idx]);
    wvb[idx] = f2bf(wv[idx]);
    int f = idx / E_, e = idx - f * E_;
    wtb[idx] = f2bf(btw[(size_t)e * E_ + f]);
}

// ---------------------------------------------------------------------------
// K1: cl = (x*std+mean) @ mat, with 61-zero pad both sides -> [512,5120]
// ---------------------------------------------------------------------------
__global__ __launch_bounds__(256) void k_cl(const float* __restrict__ x,
                                            const float* __restrict__ stdv,
                                            const float* __restrict__ meanv,
                                            const float* __restrict__ mat,
                                            float* __restrict__ cl) {
    int bg = blockIdx.x, jc = blockIdx.y, tid = threadIdx.x;
    __shared__ float t[8 * 64];
    for (int idx = tid; idx < 8 * 64; idx += 256) {
        int i = idx >> 6, k = idx & 63;
        t[idx] = x[(size_t)(bg * 8 + i) * 64 + k] * stdv[k] + meanv[k];
    }
    __syncthreads();

    if (jc == 0) {
        for (int idx = tid; idx < 8 * PAD_; idx += 256) {
            int i = idx / PAD_, jj = idx - i * PAD_;
            cl[(size_t)(bg * 8 + i) * D_TRF + jj] = 0.f;
        }
    } else if (jc == 3) {
        for (int idx = tid; idx < 8 * PAD_; idx += 256) {
            int i = idx / PAD_, jj = idx - i * PAD_;
            cl[(size_t)(bg * 8 + i) * D_TRF + (D_TRF - PAD_) + jj] = 0.f;
        }
    }

    int j0 = jc * 1250;
    int jend = min(D_CL, j0 + 1250);
    for (int j = j0 + tid; j < jend; j += 256) {
        float acc[8] = {};
        #pragma unroll 16
        for (int k = 0; k < 64; ++k) {
            float m = mat[(size_t)k * D_CL + j];
            #pragma unroll
            for (int i = 0; i < 8; ++i) acc[i] += t[i * 64 + k] * m;
        }
        #pragma unroll
        for (int i = 0; i < 8; ++i)
            cl[(size_t)(bg * 8 + i) * D_TRF + PAD_ + j] = acc[i];
    }
}

// ---------------------------------------------------------------------------
// K3456 v3: fused LN + QKV + attention + Better_Transformer, one block per b,
// 8 waves. v2 (21.7 us) + this round: LayerNorm computed IN-KERNEL from the
// staged cl row (k_ln deleted; xn buffer gone; xn-staging loads gone).
// LDS 68096 B -> 2 blocks/CU:
//   clh  f32 [32][160] 20480 (cl -> h in-place)
//   Qlds/Klds bf16 [32][168] 2x10752 (LN-reduce scratch early; dead after QK^T)
//   Vtl bf16 [160][40] 12800    Satt bf16 [32][40] 2560
//   xnl bf16 [32][168] 10752 (xn -> x2 in-place)
// ---------------------------------------------------------------------------
__global__ __launch_bounds__(512) void k_qab(const float* __restrict__ cl,
                                             const float* __restrict__ ln_g,
                                             const float* __restrict__ ln_b,
                                             const unsigned short* __restrict__ wqb,
                                             const unsigned short* __restrict__ wkb,
                                             const unsigned short* __restrict__ wvb,
                                             const unsigned short* __restrict__ wtb,
                                             const float* __restrict__ bq,
                                             const float* __restrict__ bk,
                                             const float* __restrict__ bv,
                                             const float* __restrict__ bt_b,
                                             const float* __restrict__ bt_gain,
                                             const float* __restrict__ bt_bias,
                                             const float* __restrict__ sup_g,
                                             const float* __restrict__ sup_b,
                                             unsigned short* __restrict__ yb) {
    __shared__ __align__(16) char smem[68096];
    float*          clh  = (float*)smem;                              // [32][160] cl -> h
    unsigned short* Qlds = (unsigned short*)(smem + 20480);           // [32][168]
    unsigned short* Klds = Qlds + 32 * 168;                           // [32][168]
    unsigned short* Vtl  = (unsigned short*)(smem + 41984);           // [160][40]
    unsigned short* Satt = (unsigned short*)(smem + 54784);           // [32][40]
    unsigned short* xnl  = (unsigned short*)(smem + 57344);           // [32][168] -> x2

    int b = blockIdx.x;
    int tid = threadIdx.x, wid = tid >> 6, lane = tid & 63;
    int l32 = lane & 31, hi = lane >> 5;

    // ---- stage cl[b] (5120 f32 = 1280 x 16B) via global_load_lds ----
    const float* clg = cl + (size_t)b * D_TRF;
    #pragma unroll
    for (int it = 0; it < 3; ++it) {
        int u = it * 512 + tid;
        if (u < 1280)
            load_lds16(clg + u * 4, (char*)clh + (size_t)u * 16);
    }
    __syncthreads();   // drains vmcnt: cl staged

    // ---- LayerNorm over the 5120-row (in-LDS); xnl = LN(cl) bf16 ----
    {
        float s = 0.f, s2 = 0.f;
        #pragma unroll
        for (int it = 0; it < 10; ++it) {
            float v = clh[it * 512 + tid];
            s += v; s2 += v * v;
        }
        #pragma unroll
        for (int off = 32; off; off >>= 1) {
            s  += __shfl_down(s, off);
            s2 += __shfl_down(s2, off);
        }
        float* red = (float*)Qlds;   // scratch before Q is written
        if (lane == 0) { red[wid] = s; red[8 + wid] = s2; }
        __syncthreads();
        if (tid == 0) {
            float S = 0.f, S2 = 0.f;
            #pragma unroll
            for (int i = 0; i < 8; ++i) { S += red[i]; S2 += red[8 + i]; }
            float mu = S / (float)D_TRF;
            float var = S2 / (float)D_TRF - mu * mu;
            red[16] = mu; red[17] = rsqrtf(var + 1e-5f);
        }
        __syncthreads();
        float mu = red[16], rs = red[17];
        #pragma unroll
        for (int it = 0; it < 10; ++it) {
            int idx = it * 512 + tid;
            int p = idx / 160, e = idx - p * 160;
            xnl[p * 168 + e] = f2bf((clh[idx] - mu) * rs * ln_g[idx] + ln_b[idx]);
        }
    }
    __syncthreads();   // xnl ready; Qlds scratch reads done

    // ---- QKV: 15 32x32 tiles (3 mats x 5 col-tiles), 8 waves strided ----
    for (int tc = wid; tc < 15; tc += 8) {
        int mat = tc / 5, f0 = (tc - mat * 5) * 32;
        const unsigned short* wsrc = (mat == 0) ? wqb : (mat == 1) ? wkb : wvb;
        const float* bias          = (mat == 0) ? bq  : (mat == 1) ? bk  : bv;
        floatx16 acc = {0.f, 0.f, 0.f, 0.f, 0.f, 0.f, 0.f, 0.f,
                        0.f, 0.f, 0.f, 0.f, 0.f, 0.f, 0.f, 0.f};
        #pragma unroll
        for (int kc = 0; kc < 10; ++kc) {
            int e0 = kc * 16;
            short8 af = *(const short8*)(xnl + l32 * 168 + e0 + hi * 8);
            short8 bf = *(const short8*)(wsrc + (size_t)(f0 + l32) * E_ + e0 + hi * 8);
            acc = __builtin_amdgcn_mfma_f32_32x32x16_bf16(af, bf, acc, 0, 0, 0);
        }
        int f = f0 + l32;
        float bb = bias[f];
        if (mat == 0) {
            #pragma unroll
            for (int r = 0; r < 16; ++r) {
                int p = (r & 3) + 8 * (r >> 2) + 4 * hi;
                Qlds[p * 168 + f] = f2bf(acc[r] + bb);
            }
        } else if (mat == 1) {
            #pragma unroll
            for (int r = 0; r < 16; ++r) {
                int p = (r & 3) + 8 * (r >> 2) + 4 * hi;
                Klds[p * 168 + f] = f2bf(acc[r] + bb);
            }
        } else {
            #pragma unroll
            for (int r = 0; r < 16; ++r) {
                int p = (r & 3) + 8 * (r >> 2) + 4 * hi;
                Vtl[f * 40 + p] = f2bf(acc[r] + bb);   // transposed: [e][q]
            }
        }
    }
    __syncthreads();

    // ---- S = Q K^T + softmax over p: wave 0 only ----
    if (wid == 0) {
        floatx16 S = {0.f, 0.f, 0.f, 0.f, 0.f, 0.f, 0.f, 0.f,
                      0.f, 0.f, 0.f, 0.f, 0.f, 0.f, 0.f, 0.f};
        #pragma unroll
        for (int kc = 0; kc < 10; ++kc) {
            int e0 = kc * 16;
            short8 aq = *(const short8*)(Qlds + l32 * 168 + e0 + hi * 8);
            short8 bk2 = *(const short8*)(Klds + l32 * 168 + e0 + hi * 8);
            S = __builtin_amdgcn_mfma_f32_32x32x16_bf16(aq, bk2, S, 0, 0, 0);
        }
        float mx = -1e30f;
        #pragma unroll
        for (int r = 0; r < 16; ++r) { S[r] *= INV_SCALE; mx = fmaxf(mx, S[r]); }
        mx = fmaxf(mx, __shfl_xor(mx, 32));
        float ex[16];
        float sum = 0.f;
        #pragma unroll
        for (int r = 0; r < 16; ++r) { ex[r] = __expf(S[r] - mx); sum += ex[r]; }
        sum += __shfl_xor(sum, 32);
        float inv = 1.f / sum;
        #pragma unroll
        for (int r = 0; r < 16; ++r) {
            int p = (r & 3) + 8 * (r >> 2) + 4 * hi;
            Satt[p * 40 + l32] = f2bf(ex[r] * inv);
        }
    }
    __syncthreads();   // att ready; Q/K dead

    // ---- PV + residual: h = att.V + cl, in LDS (clh in-place) ----
    short8 a0 = *(const short8*)(Satt + l32 * 40 + hi * 8);
    short8 a1 = *(const short8*)(Satt + l32 * 40 + 16 + hi * 8);
    float gg = bt_gain[0], bb2 = bt_bias[0];
    if (wid < 5) {
        int e0 = wid * 32;
        short8 b0 = *(const short8*)(Vtl + (e0 + l32) * 40 + hi * 8);
        short8 b1 = *(const short8*)(Vtl + (e0 + l32) * 40 + 16 + hi * 8);
        floatx16 acc = {0.f, 0.f, 0.f, 0.f, 0.f, 0.f, 0.f, 0.f,
                        0.f, 0.f, 0.f, 0.f, 0.f, 0.f, 0.f, 0.f};
        acc = __builtin_amdgcn_mfma_f32_32x32x16_bf16(a0, b0, acc, 0, 0, 0);
        acc = __builtin_amdgcn_mfma_f32_32x32x16_bf16(a1, b1, acc, 0, 0, 0);
        #pragma unroll
        for (int r = 0; r < 16; ++r) {
            int p = (r & 3) + 8 * (r >> 2) + 4 * hi;
            int e = e0 + l32;
            float hv = acc[r] + clh[p * E_ + e];   // read cl, then overwrite as h
            clh[p * E_ + e] = hv;
            xnl[p * 168 + e] = f2bf(hv * gg + bb2);   // x2
        }
    }
    __syncthreads();   // h, x2 ready

    // ---- BT: o = x2 @ bt_w + bt_b; supact; + h -> yb ----
    if (wid < 5) {
        int f0 = wid * 32;
        floatx16 acc = {0.f, 0.f, 0.f, 0.f, 0.f, 0.f, 0.f, 0.f,
                        0.f, 0.f, 0.f, 0.f, 0.f, 0.f, 0.f, 0.f};
        #pragma unroll
        for (int kc = 0; kc < 10; ++kc) {
            int e0 = kc * 16;
            short8 af = *(const short8*)(xnl + l32 * 168 + e0 + hi * 8);
            short8 bf = *(const short8*)(wtb + (size_t)(f0 + l32) * E_ + e0 + hi * 8);
            acc = __builtin_amdgcn_mfma_f32_32x32x16_bf16(af, bf, acc, 0, 0, 0);
        }
        int f = f0 + l32;
        float bb = bt_b[f];
        #pragma unroll
        for (int r = 0; r < 16; ++r) {
            int p = (r & 3) + 8 * (r >> 2) + 4 * hi;
            int i = p * E_ + f;
            float o = acc[r] + bb;
            float sig = 1.f / (1.f + __expf(-sup_b[i] * o));
            float y = (sup_g[i] + sig * (1.f - sup_g[i])) * o + clh[p * E_ + f];
            yb[((size_t)b * 32 + p) * E_ + f] = f2bf(y);
        }
    }
}

// ---------------------------------------------------------------------------
// K7 v11: head GEMM, B staged DIRECTLY from f32 lin_w with in-kernel bf16
// cast (k_castw deleted: saves its ~92 MB traffic + kernel + launch).
// A path unchanged (gload_lds of yb, 4 insts/wave). B path: 6 f32x4 loads ->
// regs (ping-pong bP/bN) -> pack bf16 -> 3 ds_write_b128, same final XOR-
// chunk LDS layout as before (read side untouched). Pad rows >=3000 zeroed.
// vmcnt schedule (invariant: entering iter t, outstanding=[B(t)6,A(t)4]):
//   issue B(t+1),A(t+1) -> 20; vmcnt(14) drains B(t); ds_write B(t);
//   vmcnt(10) drains A(t); lgkm(0); barrier; compute; lgkm(0); barrier.
// All loads/stores pinned by the memory-clobber asm (cannot cross).
// ---------------------------------------------------------------------------
__global__ __launch_bounds__(256, 2) void k_lin11(const unsigned short* __restrict__ yb,
                                                  const float* __restrict__ w,
                                                  float* __restrict__ pb) {
    __shared__ __align__(16) unsigned short As[2][128 * 64];  // 2 x 16 KB
    __shared__ __align__(16) unsigned short Bs[2][96 * 64];   // 2 x 12 KB

    int bid = blockIdx.x;
    int xcd = bid & 7, j = bid >> 3;
    int nt = xcd * 4 + (j & 3);          // 0..31  (96-col tiles)
    int mt = (j >> 2) & 3;               // 0..3   (128-row tiles)
    int sp = j >> 4;                     // 0..3   (split-K, 1280 each)

    int tid = threadIdx.x, wid = tid >> 6, lane = tid & 63;
    int l16 = lane & 15, quad = lane >> 4;
    int wr = wid >> 1, wc = wid & 1;     // 2x2 wave grid

    const size_t aRow0 = (size_t)(mt * 128) * D_TRF;
    const int k0 = sp * 1280;

    floatx4 acc[4][3];
    #pragma unroll
    for (int fi = 0; fi < 4; ++fi)
        #pragma unroll
        for (int fj = 0; fj < 3; ++fj) acc[fi][fj] = (floatx4){0.f, 0.f, 0.f, 0.f};

    int aOff[4][2], bOff[3][2];
    #pragma unroll
    for (int fi = 0; fi < 4; ++fi) {
        int row = wr * 64 + fi * 16 + l16;
        #pragma unroll
        for (int kk = 0; kk < 2; ++kk)
            aOff[fi][kk] = row * 64 + (((quad + kk * 4) ^ (row & 7)) * 8);
    }
    #pragma unroll
    for (int fj = 0; fj < 3; ++fj) {
        int row = wc * 48 + fj * 16 + l16;
        #pragma unroll
        for (int kk = 0; kk < 2; ++kk)
            bOff[fj][kk] = row * 64 + (((quad + kk * 4) ^ (row & 7)) * 8);
    }

    // B-tile slot decode for this thread (3 slots of 16B-bf16 = 8 cols each)
    int bRowG[3], bColG[3];
    #pragma unroll
    for (int s = 0; s < 3; ++s) {
        int u = s * 256 + tid;
        int row = u >> 3, c = u & 7;
        bRowG[s] = nt * 96 + row;            // global lin_w row
        bColG[s] = (c ^ (row & 7)) * 8;      // global col chunk (XOR swizzle)
    }

    float4 bP[3][2], bN[3][2];

#define LOADB11(DST, t)                                                         \
    do {                                                                        \
        int kh_ = k0 + (t) * 64;                                                \
        _Pragma("unroll")                                                       \
        for (int s_ = 0; s_ < 3; ++s_) {                                        \
            if (bRowG[s_] < D_OUT) {                                            \
                const float* src_ = w + (size_t)bRowG[s_] * D_TRF + kh_ + bColG[s_]; \
                DST[s_][0] = *(const float4*)(src_);                            \
                DST[s_][1] = *(const float4*)(src_ + 4);                        \
            } else {                                                            \
                DST[s_][0] = (float4){0.f, 0.f, 0.f, 0.f};                      \
                DST[s_][1] = (float4){0.f, 0.f, 0.f, 0.f};                      \
            }                                                                   \
        }                                                                       \
    } while (0)

#define WRITEB11(SRC, buf)                                                      \
    do {                                                                        \
        _Pragma("unroll")                                                       \
        for (int s_ = 0; s_ < 3; ++s_) {                                        \
            int u_ = s_ * 256 + tid;                                            \
            *(short8*)((char*)(&Bs[buf][0]) + (size_t)u_ * 16) =                \
                pack8(SRC[s_][0], SRC[s_][1]);                                  \
        }                                                                       \
    } while (0)

#define STAGEA11(buf, t)                                                        \
    do {                                                                        \
        int kh_ = k0 + (t) * 64;                                                \
        _Pragma("unroll")                                                       \
        for (int i_ = 0; i_ < 4; ++i_) {                                        \
            int u_ = i_ * 256 + tid;                                            \
            int row_ = u_ >> 3, c_ = u_ & 7;                                    \
            load_lds16(yb + aRow0 + (size_t)row_ * D_TRF + kh_ +                \
                           ((c_ ^ (row_ & 7)) * 8),                             \
                       (char*)(&As[buf][0]) + (size_t)u_ * 16);                 \
        }                                                                       \
    } while (0)

#define COMPUTE11(cur)                                                          \
    do {                                                                        \
        const unsigned short* Ab = &As[cur][0];                                 \
        const unsigned short* Bb = &Bs[cur][0];                                 \
        short8 af[4][2], bfr[3][2];                                             \
        _Pragma("unroll")                                                       \
        for (int fi = 0; fi < 4; ++fi)                                          \
            _Pragma("unroll")                                                   \
            for (int kk = 0; kk < 2; ++kk)                                      \
                af[fi][kk] = *(const short8*)(Ab + aOff[fi][kk]);               \
        _Pragma("unroll")                                                       \
        for (int fj = 0; fj < 3; ++fj)                                          \
            _Pragma("unroll")                                                   \
            for (int kk = 0; kk < 2; ++kk)                                      \
                bfr[fj][kk] = *(const short8*)(Bb + bOff[fj][kk]);              \
        _Pragma("unroll")                                                       \
        for (int kk = 0; kk < 2; ++kk)                                          \
            _Pragma("unroll")                                                   \
            for (int fi = 0; fi < 4; ++fi)                                      \
                _Pragma("unroll")                                               \
                for (int fj = 0; fj < 3; ++fj)                                  \
                    acc[fi][fj] = __builtin_amdgcn_mfma_f32_16x16x32_bf16(      \
                        af[fi][kk], bfr[fj][kk], acc[fi][fj], 0, 0, 0);         \
    } while (0)

#define PHASE11(t, WREG, LREG)                                                  \
    do {                                                                        \
        const int cur_ = (t) & 1;                                               \
        if ((t) < 19) {                                                         \
            LOADB11(LREG, (t) + 1);                                             \
            STAGEA11(cur_ ^ 1, (t) + 1);                                        \
            asm volatile("s_waitcnt vmcnt(14)" ::: "memory");  /* B(t) done */  \
            WRITEB11(WREG, cur_);                                               \
            asm volatile("s_waitcnt vmcnt(10)" ::: "memory");  /* A(t) done */  \
        } else {                                                                \
            asm volatile("s_waitcnt vmcnt(4)" ::: "memory");   /* B(19) done */ \
            WRITEB11(WREG, cur_);                                               \
            asm volatile("s_waitcnt vmcnt(0)" ::: "memory");   /* A(19) done */ \
        }                                                                       \
        asm volatile("s_waitcnt lgkmcnt(0)" ::: "memory");     /* ds_writes */  \
        __builtin_amdgcn_s_barrier();                                           \
        COMPUTE11(cur_);                                                        \
        asm volatile("s_waitcnt lgkmcnt(0)" ::: "memory");     /* ds_reads */   \
        __builtin_amdgcn_s_barrier();                                           \
    } while (0)

    LOADB11(bP, 0);      // 6 vmem
    STAGEA11(0, 0);      // 4 vmem  -> invariant [B0(6), A0(4)]

    for (int it = 0; it < 10; ++it) {
        PHASE11(2 * it,     bP, bN);
        PHASE11(2 * it + 1, bN, bP);
    }
#undef PHASE11
#undef COMPUTE11
#undef STAGEA11
#undef WRITEB11
#undef LOADB11

    // epilogue: coalesced partial stores
    #pragma unroll
    for (int fi = 0; fi < 4; ++fi) {
        int row = mt * 128 + wr * 64 + fi * 16 + quad * 4;
        #pragma unroll
        for (int fj = 0; fj < 3; ++fj) {
            int col = nt * 96 + wc * 48 + fj * 16 + l16;
            #pragma unroll
            for (int r = 0; r < 4; ++r)
                pb[((size_t)(sp * 512 + row + r)) * 3072 + col] = acc[fi][fj][r];
        }
    }
}

// ---------------------------------------------------------------------------
// K8: reduce 4 split-K partials + bias/gain -> out [512,3000]
// ---------------------------------------------------------------------------
__global__ __launch_bounds__(256) void k_red(const float* __restrict__ pb,
                                             const float* __restrict__ lin_b,
                                             const float* __restrict__ out_gain,
                                             const float* __restrict__ out_bias,
                                             float* __restrict__ out) {
    int col = blockIdx.x * 256 + threadIdx.x;
    if (col >= D_OUT) return;
    int row = blockIdx.y;
    size_t base = (size_t)row * 3072 + col;
    const size_t stride = (size_t)512 * 3072;
    float s = pb[base] + pb[base + stride] + pb[base + 2 * stride] + pb[base + 3 * stride];
    float g = out_gain[0];
    out[(size_t)row * D_OUT + col] = s * g + lin_b[col] * g + out_bias[0];
}

// ---------------------------------------------------------------------------
// Workspace layout (bytes)
// ---------------------------------------------------------------------------
#define SZ_ROWF ((size_t)B_ * D_TRF * 4)           // 10,485,760
#define SZ_ROWB ((size_t)B_ * D_TRF * 2)           // 5,242,880
#define OFF_CL  ((size_t)0)
#define OFF_YB  (OFF_CL + SZ_ROWF + SZ_ROWF + 4 * SZ_ROWB)   // keep legacy spacing
#define OFF_WSM (OFF_YB + SZ_ROWB)                 // 4 x 51200 B
// pb (4*512*3072*4 = 25,165,824 B) aliases OFF_CL..: cl is dead once k_qab
// has run, and 25.2 MB < OFF_YB (41.9 MB) -> yb untouched.

extern "C" void kernel_launch(void* const* d_in, const int* in_sizes, int n_in,
                              void* d_out, int out_size, void* d_ws, size_t ws_size,
                              hipStream_t stream) {
    const float* x        = (const float*)d_in[0];
    const float* stdv     = (const float*)d_in[1];
    const float* meanv    = (const float*)d_in[2];
    const float* mat      = (const float*)d_in[3];
    const float* ln_g     = (const float*)d_in[4];
    const float* ln_b     = (const float*)d_in[5];
    const float* wq       = (const float*)d_in[6];
    const float* bq       = (const float*)d_in[7];
    const float* wk       = (const float*)d_in[8];
    const float* bk       = (const float*)d_in[9];
    const float* wv       = (const float*)d_in[10];
    const float* bv       = (const float*)d_in[11];
    const float* bt_w     = (const float*)d_in[12];
    const float* bt_b     = (const float*)d_in[13];
    const float* bt_gain  = (const float*)d_in[14];
    const float* bt_bias  = (const float*)d_in[15];
    const float* sup_g    = (const float*)d_in[16];
    const float* sup_b    = (const float*)d_in[17];
    const float* lin_w    = (const float*)d_in[18];
    const float* lin_b    = (const float*)d_in[19];
    const float* out_gain = (const float*)d_in[20];
    const float* out_bias = (const float*)d_in[21];

    char* ws = (char*)d_ws;
    float* cl = (float*)(ws + OFF_CL);
    unsigned short* yb  = (unsigned short*)(ws + OFF_YB);
    unsigned short* wqb = (unsigned short*)(ws + OFF_WSM);
    unsigned short* wkb = wqb + E_ * E_;
    unsigned short* wvb = wkb + E_ * E_;
    unsigned short* wtb = wvb + E_ * E_;
    float* pb = (float*)(ws + OFF_CL);   // aliases cl (dead by k_lin11)
    float* out = (float*)d_out;

    k_cast_small<<<100, 256, 0, stream>>>(wq, wk, wv, bt_w, wqb, wkb, wvb, wtb);
    k_cl<<<dim3(64, 4), 256, 0, stream>>>(x, stdv, meanv, mat, cl);
    k_qab<<<512, 512, 0, stream>>>(cl, ln_g, ln_b, wqb, wkb, wvb, wtb,
                                   bq, bk, bv, bt_b, bt_gain, bt_bias,
                                   sup_g, sup_b, yb);
    k_lin11<<<512, 256, 0, stream>>>(yb, lin_w, pb);
    k_red<<<dim3(12, 512), 256, 0, stream>>>(pb, lin_b, out_gain, out_bias, out);
}